// Round 2
// baseline (1012.049 us; speedup 1.0000x reference)
//
#include <hip/hip_runtime.h>
#include <math.h>

#define IMG_H 512
#define IMG_W 512

// ---------------------------------------------------------------------------
// Pass 1: conv1 (4->32, 3x3, SAME) + ReLU + per-(n,c) spatial sum.
// Lane mapping: lane = half*32 + oc  (2 pixels per wave-iteration, 32 ch).
// Weights in VGPRs (36/lane), x taps broadcast from LDS.
// ---------------------------------------------------------------------------
__global__ __launch_bounds__(256) void k_pool(
    const float* __restrict__ x, const float* __restrict__ w1,
    const float* __restrict__ b1, float* __restrict__ red_out,
    int use_atomic) {
  __shared__ float xs[4][18][18];
  __shared__ float w1s[32][36];
  __shared__ float wsum[4][32];
  const int n = blockIdx.z;
  const int tx0 = blockIdx.x * 16, ty0 = blockIdx.y * 16;
  const int t = threadIdx.x;

  for (int i = t; i < 1152; i += 256) w1s[i / 36][i % 36] = w1[i];
  for (int i = t; i < 4 * 18 * 18; i += 256) {
    int ic = i / 324, r = i % 324, yy = r / 18, xx = r % 18;
    int gy = ty0 + yy - 1, gx = tx0 + xx - 1;
    float v = 0.f;
    if (gy >= 0 && gy < IMG_H && gx >= 0 && gx < IMG_W)
      v = x[((n * 4 + ic) * IMG_H + gy) * IMG_W + gx];
    xs[ic][yy][xx] = v;
  }
  __syncthreads();

  const int lane = t & 63, wv = t >> 6;
  const int oc = lane & 31, half = lane >> 5;
  float wreg[36];
#pragma unroll
  for (int k = 0; k < 36; ++k) wreg[k] = w1s[oc][k];
  const float bb = b1[oc];
  float lsum = 0.f;
  for (int p2 = wv; p2 < 128; p2 += 4) {
    int p = p2 * 2 + half;
    int py = p >> 4, px = p & 15;
    float acc = bb;
#pragma unroll
    for (int ic = 0; ic < 4; ++ic)
#pragma unroll
      for (int dy = 0; dy < 3; ++dy)
#pragma unroll
        for (int dx = 0; dx < 3; ++dx)
          acc += wreg[ic * 9 + dy * 3 + dx] * xs[ic][py + dy][px + dx];
    lsum += fmaxf(acc, 0.f);
  }
  lsum += __shfl_xor(lsum, 32);
  if (lane < 32) wsum[wv][oc] = lsum;
  __syncthreads();
  if (t < 32) {
    float s = wsum[0][t] + wsum[1][t] + wsum[2][t] + wsum[3][t];
    if (use_atomic) {
      atomicAdd(&red_out[n * 32 + t], s);
    } else {
      int tile = (n * 1024 + (int)blockIdx.y * 32 + (int)blockIdx.x);
      red_out[tile * 32 + t] = s;
    }
  }
}

// Deterministic reduction of per-tile partials -> sums[16][32]
__global__ __launch_bounds__(256) void k_reduce(
    const float* __restrict__ partials, float* __restrict__ sums) {
  const int n = blockIdx.x, t = threadIdx.x;
  const int c = t & 31, s = t >> 5;  // 8 stripes of 128 tiles
  float a = 0.f;
  for (int i = s * 128; i < s * 128 + 128; ++i)
    a += partials[(n * 1024 + i) * 32 + c];
  __shared__ float red[8][32];
  red[s][c] = a;
  __syncthreads();
  if (t < 32) {
    float v = 0.f;
#pragma unroll
    for (int s2 = 0; s2 < 8; ++s2) v += red[s2][t];
    sums[n * 32 + t] = v;
  }
}

// ---------------------------------------------------------------------------
// Pass 2: SE head. mean -> 1x1 conv (32->16) + ReLU -> 1x1 conv (16->32)
// -> sigmoid -> fold scale into w2:  w2p[n][oc][c][tap] = w2[...] * p[n][c]
// ---------------------------------------------------------------------------
__global__ __launch_bounds__(256) void k_se(
    const float* __restrict__ sums, const float* __restrict__ w_se1,
    const float* __restrict__ b_se1, const float* __restrict__ w_se2,
    const float* __restrict__ b_se2, const float* __restrict__ w2,
    float* __restrict__ w2p) {
  const int n = blockIdx.x, t = threadIdx.x;
  __shared__ float mean_s[32], f1[16], p[32];
  if (t < 32) mean_s[t] = sums[n * 32 + t] * (1.0f / (512.0f * 512.0f));
  __syncthreads();
  if (t < 16) {
    float a = b_se1[t];
#pragma unroll
    for (int c = 0; c < 32; ++c) a += w_se1[t * 32 + c] * mean_s[c];
    f1[t] = fmaxf(a, 0.f);
  }
  __syncthreads();
  if (t < 32) {
    float a = b_se2[t];
#pragma unroll
    for (int c = 0; c < 16; ++c) a += w_se2[t * 16 + c] * f1[c];
    p[t] = 1.f / (1.f + expf(-a));
  }
  __syncthreads();
  for (int i = t; i < 1152; i += 256) {
    int c = (i / 9) & 31;
    w2p[n * 1152 + i] = w2[i] * p[c];
  }
}

// ---------------------------------------------------------------------------
// Pass 3: fused  relu(conv2(relu(conv1(x)) scaled)) * x   per 16x16 tile.
// Phase 1 lane map: (2 h-positions x 32 ch). Phase 2: (16 px x 4 out-ch),
// 4 row-accumulators per lane to amortize weight reads.
// NOTE: conv2's SAME padding zero-pads ITS input — hs halo positions outside
// the image must be 0, NOT conv1-of-zero-padded-x (that was round-1's bug).
// ---------------------------------------------------------------------------
__global__ __launch_bounds__(256) void k_main(
    const float* __restrict__ x, const float* __restrict__ w1,
    const float* __restrict__ b1, const float* __restrict__ w2p,
    const float* __restrict__ b2, float* __restrict__ out) {
  __shared__ float xs[4][20][20];
  __shared__ float hs[18][32][18];   // [y][c][x]: writes 2-way max, reads clean
  __shared__ float wbuf[4][289];     // phase1: w1 flat[1152]; phase2: w2p padded
  const int n = blockIdx.z;
  const int tx0 = blockIdx.x * 16, ty0 = blockIdx.y * 16;
  const int t = threadIdx.x;
  float* w1s = &wbuf[0][0];

  for (int i = t; i < 1152; i += 256) w1s[i] = w1[i];
  for (int i = t; i < 4 * 400; i += 256) {
    int ic = i / 400, r = i % 400, yy = r / 20, xx = r % 20;
    int gy = ty0 + yy - 2, gx = tx0 + xx - 2;
    float v = 0.f;
    if (gy >= 0 && gy < IMG_H && gx >= 0 && gx < IMG_W)
      v = x[((n * 4 + ic) * IMG_H + gy) * IMG_W + gx];
    xs[ic][yy][xx] = v;
  }
  __syncthreads();

  const int lane = t & 63, wv = t >> 6;
  {  // conv1 -> hs over 18x18 halo positions (zero outside image!)
    const int oc = lane & 31, half = lane >> 5;
    float wreg[36];
#pragma unroll
    for (int k = 0; k < 36; ++k) wreg[k] = w1s[oc * 36 + k];
    const float bb = b1[oc];
    for (int p2 = wv; p2 < 162; p2 += 4) {
      int p = p2 * 2 + half;
      int hy = p / 18, hx = p % 18;
      float acc = bb;
#pragma unroll
      for (int ic = 0; ic < 4; ++ic)
#pragma unroll
        for (int dy = 0; dy < 3; ++dy)
#pragma unroll
          for (int dx = 0; dx < 3; ++dx)
            acc += wreg[ic * 9 + dy * 3 + dx] * xs[ic][hy + dy][hx + dx];
      const int gy = ty0 + hy - 1, gx = tx0 + hx - 1;
      const bool inimg = (gy >= 0) & (gy < IMG_H) & (gx >= 0) & (gx < IMG_W);
      hs[hy][oc][hx] = inimg ? fmaxf(acc, 0.f) : 0.f;
    }
  }
  __syncthreads();
  // overwrite w1 staging with per-sample scaled w2 (padded stride 289)
  for (int i = t; i < 1152; i += 256) wbuf[i / 288][i % 288] = w2p[n * 1152 + i];
  __syncthreads();

  {  // conv2 + relu + residual multiply
    const int px = lane & 15, oc2 = lane >> 4;
    const float bb = b2[oc2];
    float acc0 = bb, acc1 = bb, acc2 = bb, acc3 = bb;
    const int r0 = wv * 4;
#pragma unroll
    for (int c = 0; c < 32; ++c)
#pragma unroll
      for (int dy = 0; dy < 3; ++dy)
#pragma unroll
        for (int dx = 0; dx < 3; ++dx) {
          float wv_ = wbuf[oc2][c * 9 + dy * 3 + dx];
          acc0 += wv_ * hs[r0 + 0 + dy][c][px + dx];
          acc1 += wv_ * hs[r0 + 1 + dy][c][px + dx];
          acc2 += wv_ * hs[r0 + 2 + dy][c][px + dx];
          acc3 += wv_ * hs[r0 + 3 + dy][c][px + dx];
        }
    const int gx = tx0 + px;
    const long plane = (long)(n * 4 + oc2) * IMG_H;
    out[(plane + ty0 + r0 + 0) * IMG_W + gx] =
        fmaxf(acc0, 0.f) * xs[oc2][r0 + 0 + 2][px + 2];
    out[(plane + ty0 + r0 + 1) * IMG_W + gx] =
        fmaxf(acc1, 0.f) * xs[oc2][r0 + 1 + 2][px + 2];
    out[(plane + ty0 + r0 + 2) * IMG_W + gx] =
        fmaxf(acc2, 0.f) * xs[oc2][r0 + 2 + 2][px + 2];
    out[(plane + ty0 + r0 + 3) * IMG_W + gx] =
        fmaxf(acc3, 0.f) * xs[oc2][r0 + 3 + 2][px + 2];
  }
}

// ---------------------------------------------------------------------------
extern "C" void kernel_launch(void* const* d_in, const int* in_sizes, int n_in,
                              void* d_out, int out_size, void* d_ws,
                              size_t ws_size, hipStream_t stream) {
  const float* x = (const float*)d_in[0];
  const float* w1 = (const float*)d_in[1];
  const float* b1 = (const float*)d_in[2];
  const float* w2 = (const float*)d_in[3];
  const float* b2 = (const float*)d_in[4];
  const float* w_se1 = (const float*)d_in[5];
  const float* b_se1 = (const float*)d_in[6];
  const float* w_se2 = (const float*)d_in[7];
  const float* b_se2 = (const float*)d_in[8];
  float* out = (float*)d_out;

  const size_t n_partials = 16384ull * 32ull;           // 2 MB
  const size_t need = (n_partials + 512 + 16 * 1152) * sizeof(float);
  float* ws = (float*)d_ws;
  float* sums;
  float* w2p;
  dim3 grid(32, 32, 16);

  if (ws_size >= need) {
    float* partials = ws;
    sums = ws + n_partials;
    w2p = sums + 512;
    k_pool<<<grid, 256, 0, stream>>>(x, w1, b1, partials, 0);
    k_reduce<<<16, 256, 0, stream>>>(partials, sums);
  } else {
    sums = ws;
    w2p = ws + 512;
    hipMemsetAsync(sums, 0, 512 * sizeof(float), stream);
    k_pool<<<grid, 256, 0, stream>>>(x, w1, b1, sums, 1);
  }
  k_se<<<16, 256, 0, stream>>>(sums, w_se1, b_se1, w_se2, b_se2, w2, w2p);
  k_main<<<grid, 256, 0, stream>>>(x, w1, b1, w2p, b2, out);
}

// Round 3
// 254.165 us; speedup vs baseline: 3.9819x; 3.9819x over previous
//
#include <hip/hip_runtime.h>
#include <math.h>

#define IMG 512

typedef __attribute__((ext_vector_type(8))) short short8;
typedef __attribute__((ext_vector_type(4))) short short4_t;
typedef __attribute__((ext_vector_type(4))) float f32x4;
typedef __attribute__((ext_vector_type(16))) float f32x16;
typedef __attribute__((ext_vector_type(2))) unsigned int u32x2;

__device__ __forceinline__ unsigned short f2bf(float f) {
  unsigned u = __builtin_bit_cast(unsigned, f);
  u += 0x7FFFu + ((u >> 16) & 1u);  // RNE
  return (unsigned short)(u >> 16);
}
__device__ __forceinline__ unsigned pack2(float a, float b) {
  return (unsigned)f2bf(a) | ((unsigned)f2bf(b) << 16);
}

// ---------------------------------------------------------------------------
// conv1 MFMA helpers: 32x32x16 bf16, logical K=48: k = kk*16 + (hi*8+j),
// (dy=kk, dxp=(hi*8+j)>>2 in 0..3 (3 = zero-weight pad), ic=j&3).
// A: row=oc=lane&31, k-group hi=lane>>5. B: col=px=lane&31, same k split.
// xs layout: channels-last bf16 [row][cx][4ic]; B frag = 2x ds_read_b64.
// ---------------------------------------------------------------------------
#define CONV1_LOAD_A_BIAS()                                                   \
  short8 A1[3];                                                               \
  {                                                                           \
    _Pragma("unroll") for (int kk = 0; kk < 3; ++kk) {                        \
      _Pragma("unroll") for (int j = 0; j < 8; ++j) {                         \
        int dxp = 2 * hi + (j >> 2), ic = j & 3;                              \
        float v = (dxp < 3) ? w1[((oc1 * 4 + ic) * 3 + kk) * 3 + dxp] : 0.f;  \
        A1[kk][j] = (short)f2bf(v);                                           \
      }                                                                       \
    }                                                                         \
  }                                                                           \
  float bias_r[16];                                                           \
  _Pragma("unroll") for (int r = 0; r < 16; ++r)                              \
      bias_r[r] = b1[(r & 3) + 8 * (r >> 2) + 4 * hi];

#define CONV1_STEP(KK, XROW)                                                  \
  {                                                                           \
    const unsigned short* p0 = &xs[((XROW) * 36 + cx0) * 4];                  \
    short4_t bl = *(const short4_t*)p0;                                       \
    short4_t bh = *(const short4_t*)(p0 + 4);                                 \
    short8 B;                                                                 \
    B[0] = bl[0]; B[1] = bl[1]; B[2] = bl[2]; B[3] = bl[3];                   \
    B[4] = bh[0]; B[5] = bh[1]; B[6] = bh[2]; B[7] = bh[3];                   \
    C = __builtin_amdgcn_mfma_f32_32x32x16_bf16(A1[KK], B, C, 0, 0, 0);       \
  }

// ---------------------------------------------------------------------------
// Pass 1: conv1+ReLU+pool over exact 32x32 tiles.
// ---------------------------------------------------------------------------
__global__ __launch_bounds__(256) void k_pool(
    const float* __restrict__ x, const float* __restrict__ w1,
    const float* __restrict__ b1, float* __restrict__ red_out, int use_atomic) {
  __shared__ unsigned short xs[34 * 36 * 4];
  __shared__ float pools[4][2][16];
  const int n = blockIdx.z;
  const int x0 = blockIdx.x * 32, y0 = blockIdx.y * 32;
  const int t = threadIdx.x;
  const int lane = t & 63, wv = t >> 6;
  const int oc1 = lane & 31, hi = lane >> 5;

  CONV1_LOAD_A_BIAS()

  // stage x rows y0-1..y0+32 (34), cols x0-1..x0+34 (35 used, 36 stride)
  for (int i = t; i < 34 * 36 * 4; i += 256) {
    int cx = i % 36, tmp = i / 36, ic = tmp & 3, row = tmp >> 2;
    int gy = y0 - 1 + row, gx = x0 - 1 + cx;
    float v = 0.f;
    if (gy >= 0 && gy < IMG && gx >= 0 && gx < IMG)
      v = x[((n * 4 + ic) * IMG + gy) * IMG + gx];
    xs[(row * 36 + cx) * 4 + ic] = f2bf(v);
  }
  __syncthreads();

  float pacc[16];
#pragma unroll
  for (int r = 0; r < 16; ++r) pacc[r] = 0.f;
  const int cx0 = (lane & 31) + 2 * hi;
  for (int yy = 0; yy < 8; ++yy) {
    const int rb = wv * 8 + yy;  // xs row of dy=0
    f32x16 C;
#pragma unroll
    for (int r = 0; r < 16; ++r) C[r] = bias_r[r];
    CONV1_STEP(0, rb + 0)
    CONV1_STEP(1, rb + 1)
    CONV1_STEP(2, rb + 2)
#pragma unroll
    for (int r = 0; r < 16; ++r) pacc[r] += fmaxf(C[r], 0.f);
  }
#pragma unroll
  for (int r = 0; r < 16; ++r) {
#pragma unroll
    for (int m = 1; m < 32; m <<= 1) pacc[r] += __shfl_xor(pacc[r], m);
  }
  if ((lane & 31) == 0) {
#pragma unroll
    for (int r = 0; r < 16; ++r) pools[wv][hi][r] = pacc[r];
  }
  __syncthreads();
  if (t < 32) {
    const int c = t;
    const int hic = (c >> 2) & 1, reg = (c & 3) + 4 * (c >> 3);
    float s = pools[0][hic][reg] + pools[1][hic][reg] + pools[2][hic][reg] +
              pools[3][hic][reg];
    if (use_atomic) {
      atomicAdd(&red_out[n * 32 + c], s);
    } else {
      int bl = (n * 16 + (int)blockIdx.y) * 16 + (int)blockIdx.x;
      red_out[bl * 32 + c] = s;
    }
  }
}

// Deterministic reduction of 256 tiles/n -> sums[16][32]
__global__ __launch_bounds__(256) void k_reduce(
    const float* __restrict__ partials, float* __restrict__ sums) {
  const int n = blockIdx.x, t = threadIdx.x;
  const int c = t & 31, s = t >> 5;
  float a = 0.f;
  for (int i = s * 32; i < s * 32 + 32; ++i)
    a += partials[(n * 256 + i) * 32 + c];
  __shared__ float red[8][32];
  red[s][c] = a;
  __syncthreads();
  if (t < 32) {
    float v = 0.f;
#pragma unroll
    for (int s2 = 0; s2 < 8; ++s2) v += red[s2][t];
    sums[n * 32 + t] = v;
  }
}

// ---------------------------------------------------------------------------
// Pass 2: SE head -> p; emit MFMA-ready scaled conv2 weights
// w2b[n][tap][oc][c] (bf16) = w2[oc][c][tap] * p[n][c]
// ---------------------------------------------------------------------------
__global__ __launch_bounds__(256) void k_se(
    const float* __restrict__ sums, const float* __restrict__ w_se1,
    const float* __restrict__ b_se1, const float* __restrict__ w_se2,
    const float* __restrict__ b_se2, const float* __restrict__ w2,
    unsigned short* __restrict__ w2b) {
  const int n = blockIdx.x, t = threadIdx.x;
  __shared__ float mean_s[32], f1[16], p[32];
  if (t < 32) mean_s[t] = sums[n * 32 + t] * (1.0f / (512.f * 512.f));
  __syncthreads();
  if (t < 16) {
    float a = b_se1[t];
#pragma unroll
    for (int c = 0; c < 32; ++c) a += w_se1[t * 32 + c] * mean_s[c];
    f1[t] = fmaxf(a, 0.f);
  }
  __syncthreads();
  if (t < 32) {
    float a = b_se2[t];
#pragma unroll
    for (int c = 0; c < 16; ++c) a += w_se2[t * 16 + c] * f1[c];
    p[t] = 1.f / (1.f + expf(-a));
  }
  __syncthreads();
  for (int i = t; i < 1152; i += 256) {
    int c = i & 31, oc = (i >> 5) & 3, tap = i >> 7;
    w2b[n * 1152 + i] = f2bf(w2[(oc * 32 + c) * 9 + tap] * p[c]);
  }
}

// ---------------------------------------------------------------------------
// Pass 3: fused conv1(bf16 MFMA) -> hs(LDS) -> conv2(bf16 MFMA) + residual.
// Tile: 30 out cols x 16 out rows. hs: [18 rows][32 px][32 c] bf16,
// 16B-block swizzle: cblock ^= (px>>1)&3 (write and read identically).
// conv2: K=288 = 9 taps x 32c; M=16 rows, rows 0..3 = oc (rest zero A).
// ---------------------------------------------------------------------------
__global__ __launch_bounds__(256) void k_main(
    const float* __restrict__ x, const float* __restrict__ w1,
    const float* __restrict__ b1, const unsigned short* __restrict__ w2b,
    const float* __restrict__ b2, float* __restrict__ out) {
  __shared__ unsigned short xs[20 * 36 * 4];
  __shared__ unsigned short hs[18 * 32 * 32];
  const int n = blockIdx.z;
  const int x0 = blockIdx.x * 30, y0 = blockIdx.y * 16;
  const int t = threadIdx.x;
  const int lane = t & 63, wv = t >> 6;
  const int oc1 = lane & 31, hi = lane >> 5;

  CONV1_LOAD_A_BIAS()

  // stage x rows y0-2..y0+17 (20), cols x0-2..x0+33 (36)
  for (int i = t; i < 20 * 36 * 4; i += 256) {
    int cx = i % 36, tmp = i / 36, ic = tmp & 3, row = tmp >> 2;
    int gy = y0 - 2 + row, gx = x0 - 2 + cx;
    float v = 0.f;
    if (gy >= 0 && gy < IMG && gx >= 0 && gx < IMG)
      v = x[((n * 4 + ic) * IMG + gy) * IMG + gx];
    xs[(row * 36 + cx) * 4 + ic] = f2bf(v);
  }
  __syncthreads();

  // ---- conv1 -> hs (zero outside image: conv2 zero-pads ITS input)
  {
    const int px = lane & 31;
    const int cx0 = px + 2 * hi;
    const int q2 = (px >> 1) & 3;
    const int gxc = x0 - 1 + px;
    const bool colok = (gxc >= 0) && (gxc < IMG);
    for (int hy = wv; hy < 18; hy += 4) {
      const int yi = y0 - 1 + hy;
      const bool ok = colok && (yi >= 0) && (yi < IMG);
      f32x16 C;
#pragma unroll
      for (int r = 0; r < 16; ++r) C[r] = bias_r[r];
      CONV1_STEP(0, hy + 0)
      CONV1_STEP(1, hy + 1)
      CONV1_STEP(2, hy + 2)
#pragma unroll
      for (int g = 0; g < 4; ++g) {
        float v0 = ok ? fmaxf(C[4 * g + 0], 0.f) : 0.f;
        float v1 = ok ? fmaxf(C[4 * g + 1], 0.f) : 0.f;
        float v2 = ok ? fmaxf(C[4 * g + 2], 0.f) : 0.f;
        float v3 = ok ? fmaxf(C[4 * g + 3], 0.f) : 0.f;
        u32x2 w;
        w[0] = pack2(v0, v1);
        w[1] = pack2(v2, v3);
        int us = hy * 1024 + px * 32 + ((g ^ q2) << 3) + (hi << 2);
        *(u32x2*)&hs[us] = w;
      }
    }
  }
  __syncthreads();

  // ---- conv2 A frags (rows>=4 zero) + bias + epilogue constants
  const int row16 = lane & 15, cg = lane >> 4;
  short8 A2[9];
  if (row16 < 4) {
#pragma unroll
    for (int kk = 0; kk < 9; ++kk)
      A2[kk] = *(const short8*)&w2b[((n * 9 + kk) * 4 + row16) * 32 + cg * 8];
  } else {
    short8 z = {0, 0, 0, 0, 0, 0, 0, 0};
#pragma unroll
    for (int kk = 0; kk < 9; ++kk) A2[kk] = z;
  }
  const float b20 = b2[0], b21 = b2[1], b22 = b2[2], b23 = b2[3];

  {
    const int grp = wv & 1;
    const int base = (wv >> 1) * 8;      // local out-row base (0 or 8)
    const int ox = grp * 16 + row16;     // local out col (valid < 30)
    const int oxb = (ox < 29) ? ox : 29; // clamp B addressing in-bounds
    const int gx = x0 + ox;
    const bool doepi = (lane < 16) && (ox < 30) && (gx < IMG);
    const int n4 = n * 4;
    short8 Bf00, Bf01, Bf02, Bf10, Bf11, Bf12, Bf20, Bf21, Bf22;

#define LOADB(S, HR)                                                          \
  {                                                                           \
    int h0 = oxb, h1 = oxb + 1, h2 = oxb + 2, hrr = (HR) * 1024;              \
    Bf##S##0 = *(const short8*)&hs[hrr + h0 * 32 +                            \
                                   ((cg ^ ((h0 >> 1) & 3)) << 3)];            \
    Bf##S##1 = *(const short8*)&hs[hrr + h1 * 32 +                            \
                                   ((cg ^ ((h1 >> 1) & 3)) << 3)];            \
    Bf##S##2 = *(const short8*)&hs[hrr + h2 * 32 +                            \
                                   ((cg ^ ((h2 >> 1) & 3)) << 3)];            \
  }

#define MFMA9(C, SA, SB, SC)                                                  \
  C = __builtin_amdgcn_mfma_f32_16x16x32_bf16(A2[0], Bf##SA##0, C, 0, 0, 0);  \
  C = __builtin_amdgcn_mfma_f32_16x16x32_bf16(A2[1], Bf##SA##1, C, 0, 0, 0);  \
  C = __builtin_amdgcn_mfma_f32_16x16x32_bf16(A2[2], Bf##SA##2, C, 0, 0, 0);  \
  C = __builtin_amdgcn_mfma_f32_16x16x32_bf16(A2[3], Bf##SB##0, C, 0, 0, 0);  \
  C = __builtin_amdgcn_mfma_f32_16x16x32_bf16(A2[4], Bf##SB##1, C, 0, 0, 0);  \
  C = __builtin_amdgcn_mfma_f32_16x16x32_bf16(A2[5], Bf##SB##2, C, 0, 0, 0);  \
  C = __builtin_amdgcn_mfma_f32_16x16x32_bf16(A2[6], Bf##SC##0, C, 0, 0, 0);  \
  C = __builtin_amdgcn_mfma_f32_16x16x32_bf16(A2[7], Bf##SC##1, C, 0, 0, 0);  \
  C = __builtin_amdgcn_mfma_f32_16x16x32_bf16(A2[8], Bf##SC##2, C, 0, 0, 0);

#define EPI(C, YL)                                                            \
  if (doepi) {                                                                \
    const int gy = y0 + base + (YL);                                          \
    long i0 = ((long)(n4 + 0) * IMG + gy) * IMG + gx;                         \
    long i1 = ((long)(n4 + 1) * IMG + gy) * IMG + gx;                         \
    long i2 = ((long)(n4 + 2) * IMG + gy) * IMG + gx;                         \
    long i3 = ((long)(n4 + 3) * IMG + gy) * IMG + gx;                         \
    out[i0] = fmaxf(C[0] + b20, 0.f) * x[i0];                                 \
    out[i1] = fmaxf(C[1] + b21, 0.f) * x[i1];                                 \
    out[i2] = fmaxf(C[2] + b22, 0.f) * x[i2];                                 \
    out[i3] = fmaxf(C[3] + b23, 0.f) * x[i3];                                 \
  }

    LOADB(0, base + 0)
    LOADB(1, base + 1)
    LOADB(2, base + 2)
    {
      f32x4 C = {0.f, 0.f, 0.f, 0.f};
      MFMA9(C, 0, 1, 2) EPI(C, 0)
    }
    LOADB(0, base + 3)
    {
      f32x4 C = {0.f, 0.f, 0.f, 0.f};
      MFMA9(C, 1, 2, 0) EPI(C, 1)
    }
    LOADB(1, base + 4)
    {
      f32x4 C = {0.f, 0.f, 0.f, 0.f};
      MFMA9(C, 2, 0, 1) EPI(C, 2)
    }
    LOADB(2, base + 5)
    {
      f32x4 C = {0.f, 0.f, 0.f, 0.f};
      MFMA9(C, 0, 1, 2) EPI(C, 3)
    }
    LOADB(0, base + 6)
    {
      f32x4 C = {0.f, 0.f, 0.f, 0.f};
      MFMA9(C, 1, 2, 0) EPI(C, 4)
    }
    LOADB(1, base + 7)
    {
      f32x4 C = {0.f, 0.f, 0.f, 0.f};
      MFMA9(C, 2, 0, 1) EPI(C, 5)
    }
    LOADB(2, base + 8)
    {
      f32x4 C = {0.f, 0.f, 0.f, 0.f};
      MFMA9(C, 0, 1, 2) EPI(C, 6)
    }
    LOADB(0, base + 9)
    {
      f32x4 C = {0.f, 0.f, 0.f, 0.f};
      MFMA9(C, 1, 2, 0) EPI(C, 7)
    }
#undef LOADB
#undef MFMA9
#undef EPI
  }
}

// ---------------------------------------------------------------------------
extern "C" void kernel_launch(void* const* d_in, const int* in_sizes, int n_in,
                              void* d_out, int out_size, void* d_ws,
                              size_t ws_size, hipStream_t stream) {
  const float* x = (const float*)d_in[0];
  const float* w1 = (const float*)d_in[1];
  const float* b1 = (const float*)d_in[2];
  const float* w2 = (const float*)d_in[3];
  const float* b2 = (const float*)d_in[4];
  const float* w_se1 = (const float*)d_in[5];
  const float* b_se1 = (const float*)d_in[6];
  const float* w_se2 = (const float*)d_in[7];
  const float* b_se2 = (const float*)d_in[8];
  float* out = (float*)d_out;
  float* ws = (float*)d_ws;

  const size_t need_full = (size_t)(512 + 4096 * 32) * 4 + 16 * 1152 * 2;
  float* sums;
  unsigned short* w2b;
  if (ws_size >= need_full) {
    sums = ws;
    float* partials = ws + 512;
    w2b = (unsigned short*)(ws + 512 + 4096 * 32);
    k_pool<<<dim3(16, 16, 16), 256, 0, stream>>>(x, w1, b1, partials, 0);
    k_reduce<<<16, 256, 0, stream>>>(partials, sums);
  } else {
    sums = ws;
    w2b = (unsigned short*)(ws + 512);
    hipMemsetAsync(sums, 0, 512 * sizeof(float), stream);
    k_pool<<<dim3(16, 16, 16), 256, 0, stream>>>(x, w1, b1, sums, 1);
  }
  k_se<<<16, 256, 0, stream>>>(sums, w_se1, b_se1, w_se2, b_se2, w2, w2b);
  k_main<<<dim3(18, 32, 16), 256, 0, stream>>>(x, w1, b1, w2b, b2, out);
}

// Round 5
// 132.048 us; speedup vs baseline: 7.6642x; 1.9248x over previous
//
#include <hip/hip_runtime.h>
#include <math.h>

#define IMG 512

typedef __attribute__((ext_vector_type(4))) short short4_t;
typedef __attribute__((ext_vector_type(8))) short short8;
typedef __attribute__((ext_vector_type(4))) float f32x4;
typedef __attribute__((ext_vector_type(16))) float f32x16;
typedef __attribute__((ext_vector_type(2))) unsigned int u32x2;

__device__ __forceinline__ unsigned short f2bf(float f) {
  unsigned u = __builtin_bit_cast(unsigned, f);
  u += 0x7FFFu + ((u >> 16) & 1u);  // RNE
  return (unsigned short)(u >> 16);
}
// packed f32x2 -> bf16x2 (RNE), single VALU op
__device__ __forceinline__ unsigned cvtpk(float lo, float hi) {
  unsigned r;
  asm("v_cvt_pk_bf16_f32 %0, %1, %2" : "=v"(r) : "v"(lo), "v"(hi));
  return r;
}

// ---------------------------------------------------------------------------
// k_prep: lane-major conv1 A-fragments.
// w1f[(kk*64+lane)*8+j] = bf16(w1[oc=lane&31][ic=j&3][kk][dxp=2*(lane>>5)+(j>>2)])
// (dxp==3 -> 0: K padded 12->16 per kk)
// ---------------------------------------------------------------------------
__global__ __launch_bounds__(256) void k_prep(const float* __restrict__ w1,
                                              unsigned short* __restrict__ w1f) {
  const int t = threadIdx.x;
  if (t < 192) {
    const int kk = t >> 6, lane = t & 63;
    const int oc = lane & 31, hi = lane >> 5;
#pragma unroll
    for (int j = 0; j < 8; ++j) {
      const int dxp = 2 * hi + (j >> 2), ic = j & 3;
      float v = (dxp < 3) ? w1[((oc * 4 + ic) * 3 + kk) * 3 + dxp] : 0.f;
      w1f[(kk * 64 + lane) * 8 + j] = f2bf(v);
    }
  }
}

// ---------------------------------------------------------------------------
// Pass 1: conv1 (bf16 MFMA 32x32x16) + ReLU + pool over exact 32x32 tiles.
// xs: channels-last bf16 [row 34][col 40][ic 4]; staged via float4 + cvt_pk.
// px -> h col x0+px (no halo needed for pooling) => col delta = x0-1-sx = 3.
// ---------------------------------------------------------------------------
__global__ __launch_bounds__(256) void k_pool(
    const float* __restrict__ x, const unsigned short* __restrict__ w1f,
    const float* __restrict__ b1, float* __restrict__ red_out, int use_atomic) {
  __shared__ unsigned short xs[34 * 40 * 4];
  __shared__ float pools[4][2][16];
  const int n = blockIdx.z;
  const int x0 = blockIdx.x * 32, y0 = blockIdx.y * 32;
  const int t = threadIdx.x, lane = t & 63, wv = t >> 6;
  const int hi = lane >> 5;

  short8 A1[3];
#pragma unroll
  for (int kk = 0; kk < 3; ++kk)
    A1[kk] = *(const short8*)&w1f[(kk * 64 + lane) * 8];
  float bias_r[16];
#pragma unroll
  for (int r = 0; r < 16; ++r) {
    float bl = b1[(r & 3) + 8 * (r >> 2)], bh = b1[(r & 3) + 8 * (r >> 2) + 4];
    bias_r[r] = hi ? bh : bl;
  }

  const int sx = x0 - 4;  // 4-aligned (x0 = 32*bx)
  const long CS = (long)IMG * IMG;
  for (int i = t; i < 340; i += 256) {
    const int row = i / 10, cb = i % 10;
    const int gy = y0 - 1 + row, gx0 = sx + cb * 4;
    f32x4 v0 = {0.f, 0.f, 0.f, 0.f}, v1 = v0, v2 = v0, v3 = v0;
    if (gy >= 0 && gy < IMG && gx0 >= 0 && gx0 < IMG) {
      const float* p = x + (((long)(n * 4) * IMG + gy) * IMG + gx0);
      v0 = *(const f32x4*)p;
      v1 = *(const f32x4*)(p + CS);
      v2 = *(const f32x4*)(p + 2 * CS);
      v3 = *(const f32x4*)(p + 3 * CS);
    }
    unsigned short* d = &xs[(row * 40 + cb * 4) * 4];
#pragma unroll
    for (int j = 0; j < 4; ++j) {
      u32x2 w;
      w[0] = cvtpk(v0[j], v1[j]);
      w[1] = cvtpk(v2[j], v3[j]);
      *(u32x2*)(d + j * 4) = w;
    }
  }
  __syncthreads();

  float pacc[16];
#pragma unroll
  for (int r = 0; r < 16; ++r) pacc[r] = 0.f;
  const int cx0 = (lane & 31) + 2 * hi + 3;  // delta = x0-1-sx = 3
  for (int yy = 0; yy < 8; ++yy) {
    const int rb = wv * 8 + yy;
    const unsigned short* p0 = &xs[(rb * 40 + cx0) * 4];
    f32x16 C;
#pragma unroll
    for (int r = 0; r < 16; ++r) C[r] = bias_r[r];
#define PSTEP(KK)                                                             \
  {                                                                           \
    short4_t bl = *(const short4_t*)(p0 + (KK)*160);                          \
    short4_t bh = *(const short4_t*)(p0 + (KK)*160 + 4);                      \
    short8 B = __builtin_shufflevector(bl, bh, 0, 1, 2, 3, 4, 5, 6, 7);       \
    C = __builtin_amdgcn_mfma_f32_32x32x16_bf16(A1[KK], B, C, 0, 0, 0);       \
  }
    PSTEP(0) PSTEP(1) PSTEP(2)
#undef PSTEP
#pragma unroll
    for (int r = 0; r < 16; ++r) pacc[r] += fmaxf(C[r], 0.f);
  }
#pragma unroll
  for (int r = 0; r < 16; ++r) {
#pragma unroll
    for (int m = 1; m < 32; m <<= 1) pacc[r] += __shfl_xor(pacc[r], m);
  }
  if ((lane & 31) == 0) {
#pragma unroll
    for (int r = 0; r < 16; ++r) pools[wv][hi][r] = pacc[r];
  }
  __syncthreads();
  if (t < 32) {
    const int c = t;
    const int hic = (c >> 2) & 1, reg = (c & 3) + 4 * (c >> 3);
    float s = pools[0][hic][reg] + pools[1][hic][reg] + pools[2][hic][reg] +
              pools[3][hic][reg];
    if (use_atomic) {
      atomicAdd(&red_out[n * 32 + c], s);
    } else {
      int bl = (n * 16 + (int)blockIdx.y) * 16 + (int)blockIdx.x;
      red_out[bl * 32 + c] = s;
    }
  }
}

// Deterministic reduction of 256 tiles/n -> sums[16][32]
__global__ __launch_bounds__(256) void k_reduce(
    const float* __restrict__ partials, float* __restrict__ sums) {
  const int n = blockIdx.x, t = threadIdx.x;
  const int c = t & 31, s = t >> 5;
  float a = 0.f;
  for (int i = s * 32; i < s * 32 + 32; ++i)
    a += partials[(n * 256 + i) * 32 + c];
  __shared__ float red[8][32];
  red[s][c] = a;
  __syncthreads();
  if (t < 32) {
    float v = 0.f;
#pragma unroll
    for (int s2 = 0; s2 < 8; ++s2) v += red[s2][t];
    sums[n * 32 + t] = v;
  }
}

// ---------------------------------------------------------------------------
// Pass 2: SE head -> p; emit lane-major MFMA-ready scaled conv2 A-fragments:
// w2f[((n*9+tap)*64+lane)*8+j] = bf16(w2[oc=lane&15][c=(lane>>4)*8+j][tap]*p[c])
// (rows oc>=4 stored as zero -> no branch in k_main)
// ---------------------------------------------------------------------------
__global__ __launch_bounds__(256) void k_se(
    const float* __restrict__ sums, const float* __restrict__ w_se1,
    const float* __restrict__ b_se1, const float* __restrict__ w_se2,
    const float* __restrict__ b_se2, const float* __restrict__ w2,
    unsigned short* __restrict__ w2f) {
  const int n = blockIdx.x, t = threadIdx.x;
  __shared__ float mean_s[32], f1[16], p[32];
  if (t < 32) mean_s[t] = sums[n * 32 + t] * (1.0f / (512.f * 512.f));
  __syncthreads();
  if (t < 16) {
    float a = b_se1[t];
#pragma unroll
    for (int c = 0; c < 32; ++c) a += w_se1[t * 32 + c] * mean_s[c];
    f1[t] = fmaxf(a, 0.f);
  }
  __syncthreads();
  if (t < 32) {
    float a = b_se2[t];
#pragma unroll
    for (int c = 0; c < 16; ++c) a += w_se2[t * 16 + c] * f1[c];
    p[t] = 1.f / (1.f + expf(-a));
  }
  __syncthreads();
  for (int i = t; i < 4608; i += 256) {
    const int tap = i >> 9, rem = i & 511, lane2 = rem >> 3, j = rem & 7;
    const int row16 = lane2 & 15, cg = lane2 >> 4;
    float v = 0.f;
    if (row16 < 4) v = w2[(row16 * 32 + (cg * 8 + j)) * 9 + tap] * p[cg * 8 + j];
    w2f[((n * 9 + tap) * 64 + lane2) * 8 + j] = f2bf(v);
  }
}

// ---------------------------------------------------------------------------
// Pass 3: fused conv1(MFMA) -> hs(LDS) -> conv2(MFMA) + residual multiply.
// Tile 30 out cols x 16 out rows. xs [20][40][4] bf16 (4-aligned col base);
// hs [18 rows][32 px][32 c] bf16 with 16B-block swizzle cblock ^= (px>>1)&3.
// conv1 B-lane px -> h col x0-1+px (left halo!), so its dxp tap reads global
// col x0-2+px+dxp => xs col delta = x0-2-sx (NOT x0-1-sx: that was round-4's
// one-column-shift bug; k_pool's delta differs because pool has no halo).
// ---------------------------------------------------------------------------
__global__ __launch_bounds__(256) void k_main(
    const float* __restrict__ x, const unsigned short* __restrict__ w1f,
    const float* __restrict__ b1, const unsigned short* __restrict__ w2f,
    const float* __restrict__ b2, float* __restrict__ out) {
  __shared__ unsigned short xs[20 * 40 * 4];
  __shared__ unsigned short hs[18 * 32 * 32];
  const int n = blockIdx.z;
  const int x0 = blockIdx.x * 30, y0 = blockIdx.y * 16;
  const int t = threadIdx.x, lane = t & 63, wv = t >> 6;
  const int hi = lane >> 5;

  short8 A1[3];
#pragma unroll
  for (int kk = 0; kk < 3; ++kk)
    A1[kk] = *(const short8*)&w1f[(kk * 64 + lane) * 8];
  float bias_r[16];
#pragma unroll
  for (int r = 0; r < 16; ++r) {
    float bl = b1[(r & 3) + 8 * (r >> 2)], bh = b1[(r & 3) + 8 * (r >> 2) + 4];
    bias_r[r] = hi ? bh : bl;
  }

  const int sx = (x0 - 4) & ~3;  // 4-aligned staging base
  const long CS = (long)IMG * IMG;
  for (int i = t; i < 200; i += 256) {
    const int row = i / 10, cb = i % 10;
    const int gy = y0 - 2 + row, gx0 = sx + cb * 4;
    f32x4 v0 = {0.f, 0.f, 0.f, 0.f}, v1 = v0, v2 = v0, v3 = v0;
    if (gy >= 0 && gy < IMG && gx0 >= 0 && gx0 < IMG) {
      const float* p = x + (((long)(n * 4) * IMG + gy) * IMG + gx0);
      v0 = *(const f32x4*)p;
      v1 = *(const f32x4*)(p + CS);
      v2 = *(const f32x4*)(p + 2 * CS);
      v3 = *(const f32x4*)(p + 3 * CS);
    }
    unsigned short* d = &xs[(row * 40 + cb * 4) * 4];
#pragma unroll
    for (int j = 0; j < 4; ++j) {
      u32x2 w;
      w[0] = cvtpk(v0[j], v1[j]);
      w[1] = cvtpk(v2[j], v3[j]);
      *(u32x2*)(d + j * 4) = w;
    }
  }
  __syncthreads();

  // ---- conv1 -> hs (hs = 0 outside image: conv2 zero-pads ITS input)
  {
    const int px = lane & 31;
    const int cx0 = px + 2 * hi + (x0 - 2 - sx);  // halo-aware delta (the fix)
    const int q2 = (px >> 1) & 3;
    const int gxc = x0 - 1 + px;
    const bool colok = (gxc >= 0) && (gxc < IMG);
    for (int hy = wv; hy < 18; hy += 4) {
      const int yi = y0 - 1 + hy;
      const bool ok = colok && (yi >= 0) && (yi < IMG);
      const unsigned short* p0 = &xs[(hy * 40 + cx0) * 4];
      f32x16 C;
#pragma unroll
      for (int r = 0; r < 16; ++r) C[r] = bias_r[r];
#define MSTEP(KK)                                                             \
  {                                                                           \
    short4_t bl = *(const short4_t*)(p0 + (KK)*160);                          \
    short4_t bh = *(const short4_t*)(p0 + (KK)*160 + 4);                      \
    short8 B = __builtin_shufflevector(bl, bh, 0, 1, 2, 3, 4, 5, 6, 7);       \
    C = __builtin_amdgcn_mfma_f32_32x32x16_bf16(A1[KK], B, C, 0, 0, 0);       \
  }
      MSTEP(0) MSTEP(1) MSTEP(2)
#undef MSTEP
#pragma unroll
      for (int g = 0; g < 4; ++g) {
        u32x2 w;
        unsigned p01 = cvtpk(fmaxf(C[4 * g + 0], 0.f), fmaxf(C[4 * g + 1], 0.f));
        unsigned p23 = cvtpk(fmaxf(C[4 * g + 2], 0.f), fmaxf(C[4 * g + 3], 0.f));
        w[0] = ok ? p01 : 0u;
        w[1] = ok ? p23 : 0u;
        const int us = hy * 1024 + px * 32 + ((g ^ q2) << 3) + (hi << 2);
        *(u32x2*)&hs[us] = w;
      }
    }
  }
  __syncthreads();

  // ---- conv2 A frags (lane-major, rows>=4 pre-zeroed) + bias
  short8 A2[9];
#pragma unroll
  for (int kk = 0; kk < 9; ++kk)
    A2[kk] = *(const short8*)&w2f[((n * 9 + kk) * 64 + lane) * 8];
  const float b20 = b2[0], b21 = b2[1], b22 = b2[2], b23 = b2[3];

  {
    const int row16 = lane & 15, cg = lane >> 4;
    const int grp = wv & 1;
    const int base = (wv >> 1) * 8;       // local out-row base (0 or 8)
    const int ox = grp * 16 + row16;      // local out col (valid < 30)
    const int oxb = (ox < 29) ? ox : 29;  // clamp B addressing in-bounds
    const int gx = x0 + ox;
    const bool doepi = (lane < 16) && (ox < 30) && (gx < IMG);
    const long ib = ((long)(n * 4) * IMG + (y0 + base)) * IMG + gx;
    short8 Bf00, Bf01, Bf02, Bf10, Bf11, Bf12, Bf20, Bf21, Bf22;

#define LOADB(S, HR)                                                          \
  {                                                                           \
    int h0 = oxb, h1 = oxb + 1, h2 = oxb + 2, hrr = (HR)*1024;                \
    Bf##S##0 = *(const short8*)&hs[hrr + h0 * 32 + ((cg ^ ((h0 >> 1) & 3)) << 3)]; \
    Bf##S##1 = *(const short8*)&hs[hrr + h1 * 32 + ((cg ^ ((h1 >> 1) & 3)) << 3)]; \
    Bf##S##2 = *(const short8*)&hs[hrr + h2 * 32 + ((cg ^ ((h2 >> 1) & 3)) << 3)]; \
  }

#define MFMA9(C, SA, SB, SC)                                                  \
  C = __builtin_amdgcn_mfma_f32_16x16x32_bf16(A2[0], Bf##SA##0, C, 0, 0, 0);  \
  C = __builtin_amdgcn_mfma_f32_16x16x32_bf16(A2[1], Bf##SA##1, C, 0, 0, 0);  \
  C = __builtin_amdgcn_mfma_f32_16x16x32_bf16(A2[2], Bf##SA##2, C, 0, 0, 0);  \
  C = __builtin_amdgcn_mfma_f32_16x16x32_bf16(A2[3], Bf##SB##0, C, 0, 0, 0);  \
  C = __builtin_amdgcn_mfma_f32_16x16x32_bf16(A2[4], Bf##SB##1, C, 0, 0, 0);  \
  C = __builtin_amdgcn_mfma_f32_16x16x32_bf16(A2[5], Bf##SB##2, C, 0, 0, 0);  \
  C = __builtin_amdgcn_mfma_f32_16x16x32_bf16(A2[6], Bf##SC##0, C, 0, 0, 0);  \
  C = __builtin_amdgcn_mfma_f32_16x16x32_bf16(A2[7], Bf##SC##1, C, 0, 0, 0);  \
  C = __builtin_amdgcn_mfma_f32_16x16x32_bf16(A2[8], Bf##SC##2, C, 0, 0, 0);

#define EPI(C, YL)                                                            \
  if (doepi) {                                                                \
    const long i0 = ib + (YL)*IMG;                                            \
    out[i0] = fmaxf(C[0] + b20, 0.f) * x[i0];                                 \
    out[i0 + CS] = fmaxf(C[1] + b21, 0.f) * x[i0 + CS];                       \
    out[i0 + 2 * CS] = fmaxf(C[2] + b22, 0.f) * x[i0 + 2 * CS];               \
    out[i0 + 3 * CS] = fmaxf(C[3] + b23, 0.f) * x[i0 + 3 * CS];               \
  }

    LOADB(0, base + 0)
    LOADB(1, base + 1)
    LOADB(2, base + 2)
    {
      f32x4 C = {0.f, 0.f, 0.f, 0.f};
      MFMA9(C, 0, 1, 2) EPI(C, 0)
    }
    LOADB(0, base + 3)
    {
      f32x4 C = {0.f, 0.f, 0.f, 0.f};
      MFMA9(C, 1, 2, 0) EPI(C, 1)
    }
    LOADB(1, base + 4)
    {
      f32x4 C = {0.f, 0.f, 0.f, 0.f};
      MFMA9(C, 2, 0, 1) EPI(C, 2)
    }
    LOADB(2, base + 5)
    {
      f32x4 C = {0.f, 0.f, 0.f, 0.f};
      MFMA9(C, 0, 1, 2) EPI(C, 3)
    }
    LOADB(0, base + 6)
    {
      f32x4 C = {0.f, 0.f, 0.f, 0.f};
      MFMA9(C, 1, 2, 0) EPI(C, 4)
    }
    LOADB(1, base + 7)
    {
      f32x4 C = {0.f, 0.f, 0.f, 0.f};
      MFMA9(C, 2, 0, 1) EPI(C, 5)
    }
    LOADB(2, base + 8)
    {
      f32x4 C = {0.f, 0.f, 0.f, 0.f};
      MFMA9(C, 0, 1, 2) EPI(C, 6)
    }
    LOADB(0, base + 9)
    {
      f32x4 C = {0.f, 0.f, 0.f, 0.f};
      MFMA9(C, 1, 2, 0) EPI(C, 7)
    }
#undef LOADB
#undef MFMA9
#undef EPI
  }
}

// ---------------------------------------------------------------------------
extern "C" void kernel_launch(void* const* d_in, const int* in_sizes, int n_in,
                              void* d_out, int out_size, void* d_ws,
                              size_t ws_size, hipStream_t stream) {
  const float* x = (const float*)d_in[0];
  const float* w1 = (const float*)d_in[1];
  const float* b1 = (const float*)d_in[2];
  const float* w2 = (const float*)d_in[3];
  const float* b2 = (const float*)d_in[4];
  const float* w_se1 = (const float*)d_in[5];
  const float* b_se1 = (const float*)d_in[6];
  const float* w_se2 = (const float*)d_in[7];
  const float* b_se2 = (const float*)d_in[8];
  float* out = (float*)d_out;
  float* ws = (float*)d_ws;

  // ws layout: sums[512] f | w1f[1536] bf16 | w2f[73728] bf16 | partials f
  float* sums = ws;
  unsigned short* w1f = (unsigned short*)(ws + 512);
  unsigned short* w2f = w1f + 1536;
  float* partials = (float*)(w2f + 73728);
  const size_t need_full =
      512 * 4 + 1536 * 2 + 73728 * 2 + (size_t)(4096 * 32) * 4;

  k_prep<<<1, 256, 0, stream>>>(w1, w1f);
  if (ws_size >= need_full) {
    k_pool<<<dim3(16, 16, 16), 256, 0, stream>>>(x, w1f, b1, partials, 0);
    k_reduce<<<16, 256, 0, stream>>>(partials, sums);
  } else {
    hipMemsetAsync(sums, 0, 512 * sizeof(float), stream);
    k_pool<<<dim3(16, 16, 16), 256, 0, stream>>>(x, w1f, b1, sums, 1);
  }
  k_se<<<16, 256, 0, stream>>>(sums, w_se1, b_se1, w_se2, b_se2, w2, w2f);
  k_main<<<dim3(18, 32, 16), 256, 0, stream>>>(x, w1f, b1, w2f, b2, out);
}

// Round 6
// 107.567 us; speedup vs baseline: 9.4086x; 1.2276x over previous
//
#include <hip/hip_runtime.h>
#include <math.h>

#define IMG 512

typedef __attribute__((ext_vector_type(4))) short short4_t;
typedef __attribute__((ext_vector_type(8))) short short8;
typedef __attribute__((ext_vector_type(4))) float f32x4;
typedef __attribute__((ext_vector_type(16))) float f32x16;
typedef __attribute__((ext_vector_type(2))) unsigned int u32x2;

__device__ __forceinline__ unsigned short f2bf(float f) {
  unsigned u = __builtin_bit_cast(unsigned, f);
  u += 0x7FFFu + ((u >> 16) & 1u);  // RNE
  return (unsigned short)(u >> 16);
}
// packed f32x2 -> bf16x2 (RNE), single VALU op
__device__ __forceinline__ unsigned cvtpk(float lo, float hi) {
  unsigned r;
  asm("v_cvt_pk_bf16_f32 %0, %1, %2" : "=v"(r) : "v"(lo), "v"(hi));
  return r;
}

// ---------------------------------------------------------------------------
// k_prep: lane-major conv1 A-fragments (32x32x16, K padded 12->16 per kk=dy).
// ---------------------------------------------------------------------------
__global__ __launch_bounds__(256) void k_prep(const float* __restrict__ w1,
                                              unsigned short* __restrict__ w1f) {
  const int t = threadIdx.x;
  if (t < 192) {
    const int kk = t >> 6, lane = t & 63;
    const int oc = lane & 31, hi = lane >> 5;
#pragma unroll
    for (int j = 0; j < 8; ++j) {
      const int dxp = 2 * hi + (j >> 2), ic = j & 3;
      float v = (dxp < 3) ? w1[((oc * 4 + ic) * 3 + kk) * 3 + dxp] : 0.f;
      w1f[(kk * 64 + lane) * 8 + j] = f2bf(v);
    }
  }
}

// ---------------------------------------------------------------------------
// Pass 1: conv1 (bf16 MFMA 32x32x16) + ReLU + pool over exact 32x32 tiles.
// xs: channels-last bf16 [row 34][col 40][ic 4]; col delta = x0-1-sx = 3.
// ---------------------------------------------------------------------------
__global__ __launch_bounds__(256) void k_pool(
    const float* __restrict__ x, const unsigned short* __restrict__ w1f,
    const float* __restrict__ b1, float* __restrict__ red_out, int use_atomic) {
  __shared__ unsigned short xs[34 * 40 * 4];
  __shared__ float pools[4][2][16];
  const int bid = blockIdx.x;
  const int swz = (bid & 7) * 512 + (bid >> 3);  // XCD-contiguous
  const int bx = swz & 15, by = (swz >> 4) & 15, n = swz >> 8;
  const int x0 = bx * 32, y0 = by * 32;
  const int t = threadIdx.x, lane = t & 63, wv = t >> 6;
  const int hi = lane >> 5;

  short8 A1[3];
#pragma unroll
  for (int kk = 0; kk < 3; ++kk)
    A1[kk] = *(const short8*)&w1f[(kk * 64 + lane) * 8];
  float bias_r[16];
#pragma unroll
  for (int r = 0; r < 16; ++r) {
    float bl = b1[(r & 3) + 8 * (r >> 2)], bh = b1[(r & 3) + 8 * (r >> 2) + 4];
    bias_r[r] = hi ? bh : bl;
  }

  const int sx = x0 - 4;
  const long CS = (long)IMG * IMG;
  for (int i = t; i < 340; i += 256) {
    const int row = i / 10, cb = i % 10;
    const int gy = y0 - 1 + row, gx0 = sx + cb * 4;
    f32x4 v0 = {0.f, 0.f, 0.f, 0.f}, v1 = v0, v2 = v0, v3 = v0;
    if (gy >= 0 && gy < IMG && gx0 >= 0 && gx0 < IMG) {
      const float* p = x + (((long)(n * 4) * IMG + gy) * IMG + gx0);
      v0 = *(const f32x4*)p;
      v1 = *(const f32x4*)(p + CS);
      v2 = *(const f32x4*)(p + 2 * CS);
      v3 = *(const f32x4*)(p + 3 * CS);
    }
    unsigned short* d = &xs[(row * 40 + cb * 4) * 4];
#pragma unroll
    for (int j = 0; j < 4; ++j) {
      u32x2 w;
      w[0] = cvtpk(v0[j], v1[j]);
      w[1] = cvtpk(v2[j], v3[j]);
      *(u32x2*)(d + j * 4) = w;
    }
  }
  __syncthreads();

  float pacc[16];
#pragma unroll
  for (int r = 0; r < 16; ++r) pacc[r] = 0.f;
  const int cx0 = (lane & 31) + 2 * hi + 3;
  for (int yy = 0; yy < 8; ++yy) {
    const int rb = wv * 8 + yy;
    const unsigned short* p0 = &xs[(rb * 40 + cx0) * 4];
    f32x16 C;
#pragma unroll
    for (int r = 0; r < 16; ++r) C[r] = bias_r[r];
#define PSTEP(KK)                                                             \
  {                                                                           \
    short4_t bl = *(const short4_t*)(p0 + (KK)*160);                          \
    short4_t bh = *(const short4_t*)(p0 + (KK)*160 + 4);                      \
    short8 B = __builtin_shufflevector(bl, bh, 0, 1, 2, 3, 4, 5, 6, 7);       \
    C = __builtin_amdgcn_mfma_f32_32x32x16_bf16(A1[KK], B, C, 0, 0, 0);       \
  }
    PSTEP(0) PSTEP(1) PSTEP(2)
#undef PSTEP
#pragma unroll
    for (int r = 0; r < 16; ++r) pacc[r] += fmaxf(C[r], 0.f);
  }
#pragma unroll
  for (int r = 0; r < 16; ++r) {
#pragma unroll
    for (int m = 1; m < 32; m <<= 1) pacc[r] += __shfl_xor(pacc[r], m);
  }
  if ((lane & 31) == 0) {
#pragma unroll
    for (int r = 0; r < 16; ++r) pools[wv][hi][r] = pacc[r];
  }
  __syncthreads();
  if (t < 32) {
    const int c = t;
    const int hic = (c >> 2) & 1, reg = (c & 3) + 4 * (c >> 3);
    float s = pools[0][hic][reg] + pools[1][hic][reg] + pools[2][hic][reg] +
              pools[3][hic][reg];
    if (use_atomic) {
      atomicAdd(&red_out[n * 32 + c], s);
    } else {
      red_out[(n * 256 + by * 16 + bx) * 32 + c] = s;
    }
  }
}

// ---------------------------------------------------------------------------
// Pass 2: reduce partials (det path) + SE head + emit conv2 A-fragments for
// the full-M K=576 scheme:
// w2f[((n*18+s)*64+lane)*8+j], s=(dyy*3+dx), lane:(row16=oc+4*yo, cg),
// value = (0<=dyy-yo<3) ? w2[oc][c=cg*8+j][dyy-yo][dx]*p[c] : 0
// ---------------------------------------------------------------------------
__global__ __launch_bounds__(256) void k_se(
    const float* __restrict__ partials, const float* __restrict__ sums,
    const float* __restrict__ w_se1, const float* __restrict__ b_se1,
    const float* __restrict__ w_se2, const float* __restrict__ b_se2,
    const float* __restrict__ w2, unsigned short* __restrict__ w2f, int det) {
  const int n = blockIdx.x, t = threadIdx.x;
  __shared__ float red[8][32];
  __shared__ float mean_s[32], f1[16], p[32];
  if (det) {
    const int c = t & 31, s = t >> 5;
    float a = 0.f;
    for (int i = s * 32; i < s * 32 + 32; ++i)
      a += partials[(n * 256 + i) * 32 + c];
    red[s][c] = a;
    __syncthreads();
    if (t < 32) {
      float v = 0.f;
#pragma unroll
      for (int s2 = 0; s2 < 8; ++s2) v += red[s2][t];
      mean_s[t] = v * (1.0f / (512.f * 512.f));
    }
  } else {
    if (t < 32) mean_s[t] = sums[n * 32 + t] * (1.0f / (512.f * 512.f));
  }
  __syncthreads();
  if (t < 16) {
    float a = b_se1[t];
#pragma unroll
    for (int c = 0; c < 32; ++c) a += w_se1[t * 32 + c] * mean_s[c];
    f1[t] = fmaxf(a, 0.f);
  }
  __syncthreads();
  if (t < 32) {
    float a = b_se2[t];
#pragma unroll
    for (int c = 0; c < 16; ++c) a += w_se2[t * 16 + c] * f1[c];
    p[t] = 1.f / (1.f + expf(-a));
  }
  __syncthreads();
  for (int i = t; i < 9216; i += 256) {
    const int s = i >> 9, rem = i & 511, lane2 = rem >> 3, j = rem & 7;
    const int oc = lane2 & 3, yo = (lane2 >> 2) & 3, cg = lane2 >> 4;
    const int c = cg * 8 + j;
    const int dyy = s / 3, dx = s - dyy * 3, dy = dyy - yo;
    float v = 0.f;
    if (dy >= 0 && dy < 3) v = w2[(oc * 32 + c) * 9 + dy * 3 + dx] * p[c];
    w2f[((n * 18 + s) * 64 + lane2) * 8 + j] = f2bf(v);
  }
}

// ---------------------------------------------------------------------------
// Pass 3: fused conv1(MFMA 32x32x16) -> hs(LDS) -> conv2(MFMA 16x16x32,
// full-M K=576) + residual multiply. Tile 30 out cols x 16 out rows.
// hs [18 rows][32 px][32 c] bf16, 16B-block swizzle cblock ^= (px>>1)&3.
// conv1 B col delta = x0-2-sx (halo-aware).
// conv2: per wave, 2 interleaved chains of 18 MFMA -> 16px x 8y x 4oc.
// ---------------------------------------------------------------------------
__global__ __launch_bounds__(256) void k_main(
    const float* __restrict__ x, const unsigned short* __restrict__ w1f,
    const float* __restrict__ b1, const unsigned short* __restrict__ w2f,
    const float* __restrict__ b2, float* __restrict__ out) {
  __shared__ unsigned short xs[20 * 40 * 4];
  __shared__ unsigned short hs[18 * 32 * 32];
  const int bid = blockIdx.x;
  const int swz = (bid & 7) * 1152 + (bid >> 3);  // XCD-contiguous
  const int bx = swz % 18;
  const int q = swz / 18;
  const int by = q & 31, n = q >> 5;
  const int x0 = bx * 30, y0 = by * 16;
  const int t = threadIdx.x, lane = t & 63, wv = t >> 6;
  const int hi = lane >> 5;

  // conv2 A-frags issued FIRST: latency hides under staging + conv1
  short8 A2[18];
#pragma unroll
  for (int s = 0; s < 18; ++s)
    A2[s] = *(const short8*)&w2f[((n * 18 + s) * 64 + lane) * 8];

  short8 A1[3];
#pragma unroll
  for (int kk = 0; kk < 3; ++kk)
    A1[kk] = *(const short8*)&w1f[(kk * 64 + lane) * 8];
  float bias_r[16];
#pragma unroll
  for (int r = 0; r < 16; ++r) {
    float bl = b1[(r & 3) + 8 * (r >> 2)], bh = b1[(r & 3) + 8 * (r >> 2) + 4];
    bias_r[r] = hi ? bh : bl;
  }

  const int sx = (x0 - 4) & ~3;
  const long CS = (long)IMG * IMG;
  for (int i = t; i < 200; i += 256) {
    const int row = i / 10, cb = i % 10;
    const int gy = y0 - 2 + row, gx0 = sx + cb * 4;
    f32x4 v0 = {0.f, 0.f, 0.f, 0.f}, v1 = v0, v2 = v0, v3 = v0;
    if (gy >= 0 && gy < IMG && gx0 >= 0 && gx0 < IMG) {
      const float* p = x + (((long)(n * 4) * IMG + gy) * IMG + gx0);
      v0 = *(const f32x4*)p;
      v1 = *(const f32x4*)(p + CS);
      v2 = *(const f32x4*)(p + 2 * CS);
      v3 = *(const f32x4*)(p + 3 * CS);
    }
    unsigned short* d = &xs[(row * 40 + cb * 4) * 4];
#pragma unroll
    for (int j = 0; j < 4; ++j) {
      u32x2 w;
      w[0] = cvtpk(v0[j], v1[j]);
      w[1] = cvtpk(v2[j], v3[j]);
      *(u32x2*)(d + j * 4) = w;
    }
  }
  __syncthreads();

  // ---- conv1 -> hs (hs = 0 outside image: conv2 zero-pads ITS input)
  {
    const int px = lane & 31;
    const int cx0 = px + 2 * hi + (x0 - 2 - sx);  // halo-aware delta
    const int q2 = (px >> 1) & 3;
    const int gxc = x0 - 1 + px;
    const bool colok = (gxc >= 0) && (gxc < IMG);
    const bool col_int = (x0 >= 1) && (x0 + 30 < IMG);  // block-uniform
    for (int hy = wv; hy < 18; hy += 4) {
      const int yi = y0 - 1 + hy;
      const bool row_ok = (yi >= 0) && (yi < IMG);  // wave-uniform
      const unsigned short* p0 = &xs[(hy * 40 + cx0) * 4];
      f32x16 C;
#pragma unroll
      for (int r = 0; r < 16; ++r) C[r] = bias_r[r];
#define MSTEP(KK)                                                             \
  {                                                                           \
    short4_t bl = *(const short4_t*)(p0 + (KK)*160);                          \
    short4_t bh = *(const short4_t*)(p0 + (KK)*160 + 4);                      \
    short8 B = __builtin_shufflevector(bl, bh, 0, 1, 2, 3, 4, 5, 6, 7);       \
    C = __builtin_amdgcn_mfma_f32_32x32x16_bf16(A1[KK], B, C, 0, 0, 0);       \
  }
      MSTEP(0) MSTEP(1) MSTEP(2)
#undef MSTEP
      const int usb = hy * 1024 + px * 32 + (hi << 2);
      if (row_ok && col_int) {  // fast path: no masks
#pragma unroll
        for (int g = 0; g < 4; ++g) {
          u32x2 w;
          w[0] = cvtpk(fmaxf(C[4 * g + 0], 0.f), fmaxf(C[4 * g + 1], 0.f));
          w[1] = cvtpk(fmaxf(C[4 * g + 2], 0.f), fmaxf(C[4 * g + 3], 0.f));
          *(u32x2*)&hs[usb + ((g ^ q2) << 3)] = w;
        }
      } else if (row_ok) {
#pragma unroll
        for (int g = 0; g < 4; ++g) {
          unsigned p01 = cvtpk(fmaxf(C[4 * g + 0], 0.f), fmaxf(C[4 * g + 1], 0.f));
          unsigned p23 = cvtpk(fmaxf(C[4 * g + 2], 0.f), fmaxf(C[4 * g + 3], 0.f));
          u32x2 w;
          w[0] = colok ? p01 : 0u;
          w[1] = colok ? p23 : 0u;
          *(u32x2*)&hs[usb + ((g ^ q2) << 3)] = w;
        }
      } else {
        u32x2 z;
        z[0] = 0u;
        z[1] = 0u;
#pragma unroll
        for (int g = 0; g < 4; ++g) *(u32x2*)&hs[usb + ((g ^ q2) << 3)] = z;
      }
    }
  }
  __syncthreads();

  // ---- conv2: 2 interleaved 18-MFMA chains per wave
  {
    const int px16 = lane & 15, cg = lane >> 4;
    const int grp = wv & 1, ybq = wv >> 1;
    const int ox = grp * 16 + px16;
    const int yo = lane >> 4;
    const int gxo = x0 + ox;
    const bool epi_ok = (ox < 30) && (gxo < IMG);
    const float b20 = b2[0], b21 = b2[1], b22 = b2[2], b23 = b2[3];
    const int n4 = n * 4;
    // 3 dx byte-bases (swizzled), clamped to hs px<=31 (clamp only hits
    // discarded cols ox=30,31)
    int ph0 = ox + 0, ph1 = ox + 1, ph2 = ox + 2;
    ph2 = ph2 < 31 ? ph2 : 31;
    ph1 = ph1 < 31 ? ph1 : 31;
    const int ba0 = ph0 * 64 + ((cg ^ ((ph0 >> 1) & 3)) << 4);
    const int ba1 = ph1 * 64 + ((cg ^ ((ph1 >> 1) & 3)) << 4);
    const int ba2 = ph2 * 64 + ((cg ^ ((ph2 >> 1) & 3)) << 4);
    const char* hbA = (const char*)hs + (ybq * 8) * 2048;
    const char* hbB = hbA + 4 * 2048;
    f32x4 CA = {0.f, 0.f, 0.f, 0.f}, CB = {0.f, 0.f, 0.f, 0.f};

#define C2(S, DYY, BA)                                                        \
  CA = __builtin_amdgcn_mfma_f32_16x16x32_bf16(                               \
      A2[S], *(const short8*)(hbA + (DYY)*2048 + (BA)), CA, 0, 0, 0);         \
  CB = __builtin_amdgcn_mfma_f32_16x16x32_bf16(                               \
      A2[S], *(const short8*)(hbB + (DYY)*2048 + (BA)), CB, 0, 0, 0);

    C2(0, 0, ba0) C2(1, 0, ba1) C2(2, 0, ba2)
    C2(3, 1, ba0) C2(4, 1, ba1) C2(5, 1, ba2)
    C2(6, 2, ba0) C2(7, 2, ba1) C2(8, 2, ba2)
    C2(9, 3, ba0) C2(10, 3, ba1) C2(11, 3, ba2)
    C2(12, 4, ba0) C2(13, 4, ba1) C2(14, 4, ba2)
    C2(15, 5, ba0) C2(16, 5, ba1) C2(17, 5, ba2)
#undef C2

#define EPI2(CV, YB)                                                          \
  if (epi_ok) {                                                               \
    const int gy = y0 + (YB) + yo;                                            \
    const long i0 = ((long)n4 * IMG + gy) * IMG + gxo;                        \
    out[i0] = fmaxf(CV[0] + b20, 0.f) * x[i0];                                \
    out[i0 + CS] = fmaxf(CV[1] + b21, 0.f) * x[i0 + CS];                      \
    out[i0 + 2 * CS] = fmaxf(CV[2] + b22, 0.f) * x[i0 + 2 * CS];              \
    out[i0 + 3 * CS] = fmaxf(CV[3] + b23, 0.f) * x[i0 + 3 * CS];              \
  }
    EPI2(CA, ybq * 8)
    EPI2(CB, ybq * 8 + 4)
#undef EPI2
  }
}

// ---------------------------------------------------------------------------
extern "C" void kernel_launch(void* const* d_in, const int* in_sizes, int n_in,
                              void* d_out, int out_size, void* d_ws,
                              size_t ws_size, hipStream_t stream) {
  const float* x = (const float*)d_in[0];
  const float* w1 = (const float*)d_in[1];
  const float* b1 = (const float*)d_in[2];
  const float* w2 = (const float*)d_in[3];
  const float* b2 = (const float*)d_in[4];
  const float* w_se1 = (const float*)d_in[5];
  const float* b_se1 = (const float*)d_in[6];
  const float* w_se2 = (const float*)d_in[7];
  const float* b_se2 = (const float*)d_in[8];
  float* out = (float*)d_out;
  float* ws = (float*)d_ws;

  // ws: sums[512]f | w1f[1536]bf16 | w2f[147456]bf16 | partials[131072]f
  float* sums = ws;
  unsigned short* w1f = (unsigned short*)(ws + 512);
  unsigned short* w2f = w1f + 1536;
  float* partials = (float*)(w2f + 147456);
  const size_t need_full =
      512 * 4 + 1536 * 2 + (size_t)147456 * 2 + (size_t)131072 * 4;

  k_prep<<<1, 256, 0, stream>>>(w1, w1f);
  if (ws_size >= need_full) {
    k_pool<<<4096, 256, 0, stream>>>(x, w1f, b1, partials, 0);
    k_se<<<16, 256, 0, stream>>>(partials, sums, w_se1, b_se1, w_se2, b_se2,
                                 w2, w2f, 1);
  } else {
    hipMemsetAsync(sums, 0, 512 * sizeof(float), stream);
    k_pool<<<4096, 256, 0, stream>>>(x, w1f, b1, sums, 1);
    k_se<<<16, 256, 0, stream>>>(partials, sums, w_se1, b_se1, w_se2, b_se2,
                                 w2, w2f, 0);
  }
  k_main<<<9216, 256, 0, stream>>>(x, w1f, b1, w2f, b2, out);
}

// Round 7
// 105.475 us; speedup vs baseline: 9.5952x; 1.0198x over previous
//
#include <hip/hip_runtime.h>
#include <math.h>

#define IMG 512

typedef __attribute__((ext_vector_type(4))) short short4_t;
typedef __attribute__((ext_vector_type(8))) short short8;
typedef __attribute__((ext_vector_type(4))) float f32x4;
typedef __attribute__((ext_vector_type(16))) float f32x16;
typedef __attribute__((ext_vector_type(2))) unsigned int u32x2;

__device__ __forceinline__ unsigned short f2bf(float f) {
  unsigned u = __builtin_bit_cast(unsigned, f);
  u += 0x7FFFu + ((u >> 16) & 1u);  // RNE
  return (unsigned short)(u >> 16);
}
// packed f32x2 -> bf16x2 (RNE), single VALU op
__device__ __forceinline__ unsigned cvtpk(float lo, float hi) {
  unsigned r;
  asm("v_cvt_pk_bf16_f32 %0, %1, %2" : "=v"(r) : "v"(lo), "v"(hi));
  return r;
}

// ---------------------------------------------------------------------------
// k_prep: lane-major conv1 A-fragments (32x32x16, K padded 12->16 per kk=dy).
// ---------------------------------------------------------------------------
__global__ __launch_bounds__(256) void k_prep(const float* __restrict__ w1,
                                              unsigned short* __restrict__ w1f) {
  const int t = threadIdx.x;
  if (t < 192) {
    const int kk = t >> 6, lane = t & 63;
    const int oc = lane & 31, hi = lane >> 5;
#pragma unroll
    for (int j = 0; j < 8; ++j) {
      const int dxp = 2 * hi + (j >> 2), ic = j & 3;
      float v = (dxp < 3) ? w1[((oc * 4 + ic) * 3 + kk) * 3 + dxp] : 0.f;
      w1f[(kk * 64 + lane) * 8 + j] = f2bf(v);
    }
  }
}

// ---------------------------------------------------------------------------
// Pass 1: conv1 (bf16 MFMA 32x32x16) + ReLU + pool over exact 32x32 tiles.
// xs: channels-last bf16 [row 34][col 40][ic 4]; col delta = x0-1-sx = 3.
// Sliding-window B-frags: consecutive rows per wave, 3-cycle reg rotation.
// ---------------------------------------------------------------------------
__global__ __launch_bounds__(256, 3) void k_pool(
    const float* __restrict__ x, const unsigned short* __restrict__ w1f,
    const float* __restrict__ b1, float* __restrict__ red_out, int use_atomic) {
  __shared__ unsigned short xs[34 * 40 * 4];
  __shared__ float pools[4][2][16];
  const int bid = blockIdx.x;
  const int swz = (bid & 7) * 512 + (bid >> 3);  // XCD-contiguous
  const int bx = swz & 15, by = (swz >> 4) & 15, n = swz >> 8;
  const int x0 = bx * 32, y0 = by * 32;
  const int t = threadIdx.x, lane = t & 63, wv = t >> 6;
  const int hi = lane >> 5;

  short8 A1[3];
#pragma unroll
  for (int kk = 0; kk < 3; ++kk)
    A1[kk] = *(const short8*)&w1f[(kk * 64 + lane) * 8];
  float bias_r[16];
#pragma unroll
  for (int r = 0; r < 16; ++r) {
    float bl = b1[(r & 3) + 8 * (r >> 2)], bh = b1[(r & 3) + 8 * (r >> 2) + 4];
    bias_r[r] = hi ? bh : bl;
  }

  const int sx = x0 - 4;
  const long CS = (long)IMG * IMG;
  for (int i = t; i < 340; i += 256) {
    const int row = i / 10, cb = i % 10;
    const int gy = y0 - 1 + row, gx0 = sx + cb * 4;
    f32x4 v0 = {0.f, 0.f, 0.f, 0.f}, v1 = v0, v2 = v0, v3 = v0;
    if (gy >= 0 && gy < IMG && gx0 >= 0 && gx0 < IMG) {
      const float* p = x + (((long)(n * 4) * IMG + gy) * IMG + gx0);
      v0 = *(const f32x4*)p;
      v1 = *(const f32x4*)(p + CS);
      v2 = *(const f32x4*)(p + 2 * CS);
      v3 = *(const f32x4*)(p + 3 * CS);
    }
    unsigned short* d = &xs[(row * 40 + cb * 4) * 4];
#pragma unroll
    for (int j = 0; j < 4; ++j) {
      u32x2 w;
      w[0] = cvtpk(v0[j], v1[j]);
      w[1] = cvtpk(v2[j], v3[j]);
      *(u32x2*)(d + j * 4) = w;
    }
  }
  __syncthreads();

  float pacc[16];
#pragma unroll
  for (int r = 0; r < 16; ++r) pacc[r] = 0.f;
  const int cx0 = (lane & 31) + 2 * hi + 3;
  const unsigned short* pP = &xs[((wv * 8) * 40 + cx0) * 4];
#define LOADP(K)                                                              \
  __builtin_shufflevector(*(const short4_t*)(pP + (K)*160),                   \
                          *(const short4_t*)(pP + (K)*160 + 4), 0, 1, 2, 3,   \
                          4, 5, 6, 7)
  short8 Ba, Bb, Bc;
  Ba = LOADP(0);
  Bb = LOADP(1);
#define P_ITER(IT, B0, B1, B2)                                                \
  {                                                                           \
    B2 = LOADP((IT) + 2);                                                     \
    f32x16 C;                                                                 \
    _Pragma("unroll") for (int r = 0; r < 16; ++r) C[r] = bias_r[r];          \
    C = __builtin_amdgcn_mfma_f32_32x32x16_bf16(A1[0], B0, C, 0, 0, 0);       \
    C = __builtin_amdgcn_mfma_f32_32x32x16_bf16(A1[1], B1, C, 0, 0, 0);       \
    C = __builtin_amdgcn_mfma_f32_32x32x16_bf16(A1[2], B2, C, 0, 0, 0);       \
    _Pragma("unroll") for (int r = 0; r < 16; ++r)                            \
        pacc[r] += fmaxf(C[r], 0.f);                                          \
  }
  P_ITER(0, Ba, Bb, Bc)
  P_ITER(1, Bb, Bc, Ba)
  P_ITER(2, Bc, Ba, Bb)
  P_ITER(3, Ba, Bb, Bc)
  P_ITER(4, Bb, Bc, Ba)
  P_ITER(5, Bc, Ba, Bb)
  P_ITER(6, Ba, Bb, Bc)
  P_ITER(7, Bb, Bc, Ba)
#undef P_ITER
#undef LOADP
#pragma unroll
  for (int r = 0; r < 16; ++r) {
#pragma unroll
    for (int m = 1; m < 32; m <<= 1) pacc[r] += __shfl_xor(pacc[r], m);
  }
  if ((lane & 31) == 0) {
#pragma unroll
    for (int r = 0; r < 16; ++r) pools[wv][hi][r] = pacc[r];
  }
  __syncthreads();
  if (t < 32) {
    const int c = t;
    const int hic = (c >> 2) & 1, reg = (c & 3) + 4 * (c >> 3);
    float s = pools[0][hic][reg] + pools[1][hic][reg] + pools[2][hic][reg] +
              pools[3][hic][reg];
    if (use_atomic) {
      atomicAdd(&red_out[n * 32 + c], s);
    } else {
      red_out[(n * 256 + by * 16 + bx) * 32 + c] = s;
    }
  }
}

// ---------------------------------------------------------------------------
// Pass 2: reduce partials (det path) + SE head + emit conv2 A-fragments:
// w2f[((n*18+s)*64+lane)*8+j], s=(dyy*3+dx), lane:(row16=oc+4*yo, cg),
// value = (0<=dyy-yo<3) ? w2[oc][c=cg*8+j][dyy-yo][dx]*p[c] : 0
// ---------------------------------------------------------------------------
__global__ __launch_bounds__(256) void k_se(
    const float* __restrict__ partials, const float* __restrict__ sums,
    const float* __restrict__ w_se1, const float* __restrict__ b_se1,
    const float* __restrict__ w_se2, const float* __restrict__ b_se2,
    const float* __restrict__ w2, unsigned short* __restrict__ w2f, int det) {
  const int n = blockIdx.x, t = threadIdx.x;
  __shared__ float red[8][32];
  __shared__ float mean_s[32], f1[16], p[32];
  if (det) {
    const int c = t & 31, s = t >> 5;
    float a = 0.f;
    for (int i = s * 32; i < s * 32 + 32; ++i)
      a += partials[(n * 256 + i) * 32 + c];
    red[s][c] = a;
    __syncthreads();
    if (t < 32) {
      float v = 0.f;
#pragma unroll
      for (int s2 = 0; s2 < 8; ++s2) v += red[s2][t];
      mean_s[t] = v * (1.0f / (512.f * 512.f));
    }
  } else {
    if (t < 32) mean_s[t] = sums[n * 32 + t] * (1.0f / (512.f * 512.f));
  }
  __syncthreads();
  if (t < 16) {
    float a = b_se1[t];
#pragma unroll
    for (int c = 0; c < 32; ++c) a += w_se1[t * 32 + c] * mean_s[c];
    f1[t] = fmaxf(a, 0.f);
  }
  __syncthreads();
  if (t < 32) {
    float a = b_se2[t];
#pragma unroll
    for (int c = 0; c < 16; ++c) a += w_se2[t * 16 + c] * f1[c];
    p[t] = 1.f / (1.f + expf(-a));
  }
  __syncthreads();
  for (int i = t; i < 9216; i += 256) {
    const int s = i >> 9, rem = i & 511, lane2 = rem >> 3, j = rem & 7;
    const int oc = lane2 & 3, yo = (lane2 >> 2) & 3, cg = lane2 >> 4;
    const int c = cg * 8 + j;
    const int dyy = s / 3, dx = s - dyy * 3, dy = dyy - yo;
    float v = 0.f;
    if (dy >= 0 && dy < 3) v = w2[(oc * 32 + c) * 9 + dy * 3 + dx] * p[c];
    w2f[((n * 18 + s) * 64 + lane2) * 8 + j] = f2bf(v);
  }
}

// ---------------------------------------------------------------------------
// Pass 3: fused conv1(MFMA 32x32x16) -> hs(LDS) -> conv2(MFMA 16x16x32,
// full-M K=576) + residual multiply. Tile 30 out cols x 16 out rows.
// hs [18 rows][32 px][32 c] bf16, swizzle q2 = ((px>>1)^(px>>3))&3 on 16B
// blocks (write and read identically). conv1 B col delta = x0-2-sx.
// conv1 uses sliding-window B-frags (consecutive rows per wave).
// conv2 A2 fragments loaded before the barrier + pinned (residency).
// ---------------------------------------------------------------------------
__global__ __launch_bounds__(256, 3) void k_main(
    const float* __restrict__ x, const unsigned short* __restrict__ w1f,
    const float* __restrict__ b1, const unsigned short* __restrict__ w2f,
    const float* __restrict__ b2, float* __restrict__ out) {
  __shared__ unsigned short xs[20 * 40 * 4];
  __shared__ unsigned short hs[18 * 32 * 32];
  const int bid = blockIdx.x;
  const int swz = (bid & 7) * 1152 + (bid >> 3);  // XCD-contiguous
  const int bx = swz % 18;
  const int q = swz / 18;
  const int by = q & 31, n = q >> 5;
  const int x0 = bx * 30, y0 = by * 16;
  const int t = threadIdx.x, lane = t & 63, wv = t >> 6;
  const int hi = lane >> 5;

  short8 A1[3];
#pragma unroll
  for (int kk = 0; kk < 3; ++kk)
    A1[kk] = *(const short8*)&w1f[(kk * 64 + lane) * 8];
  float bias_r[16];
#pragma unroll
  for (int r = 0; r < 16; ++r) {
    float bl = b1[(r & 3) + 8 * (r >> 2)], bh = b1[(r & 3) + 8 * (r >> 2) + 4];
    bias_r[r] = hi ? bh : bl;
  }

  const int sx = (x0 - 4) & ~3;
  const long CS = (long)IMG * IMG;
  for (int i = t; i < 200; i += 256) {
    const int row = i / 10, cb = i % 10;
    const int gy = y0 - 2 + row, gx0 = sx + cb * 4;
    f32x4 v0 = {0.f, 0.f, 0.f, 0.f}, v1 = v0, v2 = v0, v3 = v0;
    if (gy >= 0 && gy < IMG && gx0 >= 0 && gx0 < IMG) {
      const float* p = x + (((long)(n * 4) * IMG + gy) * IMG + gx0);
      v0 = *(const f32x4*)p;
      v1 = *(const f32x4*)(p + CS);
      v2 = *(const f32x4*)(p + 2 * CS);
      v3 = *(const f32x4*)(p + 3 * CS);
    }
    unsigned short* d = &xs[(row * 40 + cb * 4) * 4];
#pragma unroll
    for (int j = 0; j < 4; ++j) {
      u32x2 w;
      w[0] = cvtpk(v0[j], v1[j]);
      w[1] = cvtpk(v2[j], v3[j]);
      *(u32x2*)(d + j * 4) = w;
    }
  }
  __syncthreads();

  // ---- conv1 -> hs (hs = 0 outside image: conv2 zero-pads ITS input)
  {
    const int px = lane & 31;
    const int cx0 = px + 2 * hi + (x0 - 2 - sx);  // halo-aware delta
    const int q2 = ((px >> 1) ^ (px >> 3)) & 3;
    const int gxc = x0 - 1 + px;
    const bool colok = (gxc >= 0) && (gxc < IMG);
    const bool col_int = (x0 >= 1) && (x0 + 30 < IMG);  // block-uniform
    const int R0 = (wv < 2) ? wv * 5 : 10 + (wv - 2) * 4;  // rows/wave 5,5,4,4
    const unsigned short* pR = &xs[(R0 * 40 + cx0) * 4];
#define LOADX(K)                                                              \
  __builtin_shufflevector(*(const short4_t*)(pR + (K)*160),                   \
                          *(const short4_t*)(pR + (K)*160 + 4), 0, 1, 2, 3,   \
                          4, 5, 6, 7)
    short8 Ba, Bb, Bc;
    Ba = LOADX(0);
    Bb = LOADX(1);
#define C1_ITER(IT, B0, B1, B2)                                               \
  {                                                                           \
    B2 = LOADX((IT) + 2);                                                     \
    const int hy = R0 + (IT);                                                 \
    const int yi = y0 - 1 + hy;                                               \
    const bool row_ok = (yi >= 0) && (yi < IMG);                              \
    f32x16 C;                                                                 \
    _Pragma("unroll") for (int r = 0; r < 16; ++r) C[r] = bias_r[r];          \
    C = __builtin_amdgcn_mfma_f32_32x32x16_bf16(A1[0], B0, C, 0, 0, 0);       \
    C = __builtin_amdgcn_mfma_f32_32x32x16_bf16(A1[1], B1, C, 0, 0, 0);       \
    C = __builtin_amdgcn_mfma_f32_32x32x16_bf16(A1[2], B2, C, 0, 0, 0);       \
    const int usb = hy * 1024 + px * 32 + (hi << 2);                          \
    if (row_ok && col_int) {                                                  \
      _Pragma("unroll") for (int g = 0; g < 4; ++g) {                         \
        u32x2 w;                                                              \
        w[0] = cvtpk(fmaxf(C[4 * g + 0], 0.f), fmaxf(C[4 * g + 1], 0.f));     \
        w[1] = cvtpk(fmaxf(C[4 * g + 2], 0.f), fmaxf(C[4 * g + 3], 0.f));     \
        *(u32x2*)&hs[usb + ((g ^ q2) << 3)] = w;                              \
      }                                                                       \
    } else if (row_ok) {                                                      \
      _Pragma("unroll") for (int g = 0; g < 4; ++g) {                         \
        unsigned p01 =                                                        \
            cvtpk(fmaxf(C[4 * g + 0], 0.f), fmaxf(C[4 * g + 1], 0.f));        \
        unsigned p23 =                                                        \
            cvtpk(fmaxf(C[4 * g + 2], 0.f), fmaxf(C[4 * g + 3], 0.f));        \
        u32x2 w;                                                              \
        w[0] = colok ? p01 : 0u;                                              \
        w[1] = colok ? p23 : 0u;                                              \
        *(u32x2*)&hs[usb + ((g ^ q2) << 3)] = w;                              \
      }                                                                       \
    } else {                                                                  \
      u32x2 z;                                                                \
      z[0] = 0u;                                                              \
      z[1] = 0u;                                                              \
      _Pragma("unroll") for (int g = 0; g < 4; ++g)                           \
          *(u32x2*)&hs[usb + ((g ^ q2) << 3)] = z;                            \
    }                                                                         \
  }
    C1_ITER(0, Ba, Bb, Bc)
    C1_ITER(1, Bb, Bc, Ba)
    C1_ITER(2, Bc, Ba, Bb)
    C1_ITER(3, Ba, Bb, Bc)
    if (wv < 2) C1_ITER(4, Bb, Bc, Ba)
#undef C1_ITER
#undef LOADX
  }

  // ---- conv2 A-frags: issue BEFORE barrier (overlap), pin in registers
  const unsigned short* w2b = w2f + (size_t)n * 9216 + lane * 8;
  short8 A2_0 = *(const short8*)(w2b + 0 * 512);
  short8 A2_1 = *(const short8*)(w2b + 1 * 512);
  short8 A2_2 = *(const short8*)(w2b + 2 * 512);
  short8 A2_3 = *(const short8*)(w2b + 3 * 512);
  short8 A2_4 = *(const short8*)(w2b + 4 * 512);
  short8 A2_5 = *(const short8*)(w2b + 5 * 512);
  short8 A2_6 = *(const short8*)(w2b + 6 * 512);
  short8 A2_7 = *(const short8*)(w2b + 7 * 512);
  short8 A2_8 = *(const short8*)(w2b + 8 * 512);
  short8 A2_9 = *(const short8*)(w2b + 9 * 512);
  short8 A2_10 = *(const short8*)(w2b + 10 * 512);
  short8 A2_11 = *(const short8*)(w2b + 11 * 512);
  short8 A2_12 = *(const short8*)(w2b + 12 * 512);
  short8 A2_13 = *(const short8*)(w2b + 13 * 512);
  short8 A2_14 = *(const short8*)(w2b + 14 * 512);
  short8 A2_15 = *(const short8*)(w2b + 15 * 512);
  short8 A2_16 = *(const short8*)(w2b + 16 * 512);
  short8 A2_17 = *(const short8*)(w2b + 17 * 512);
  asm volatile("" ::"v"(A2_0), "v"(A2_1), "v"(A2_2), "v"(A2_3), "v"(A2_4),
               "v"(A2_5), "v"(A2_6), "v"(A2_7), "v"(A2_8), "v"(A2_9),
               "v"(A2_10), "v"(A2_11), "v"(A2_12), "v"(A2_13), "v"(A2_14),
               "v"(A2_15), "v"(A2_16), "v"(A2_17));
  __syncthreads();

  // ---- conv2: 2 interleaved 18-MFMA chains per wave
  {
    const int px16 = lane & 15, cg = lane >> 4;
    const int grp = wv & 1, ybq = wv >> 1;
    const int ox = grp * 16 + px16;
    const int yo = lane >> 4;
    const int gxo = x0 + ox;
    const bool epi_ok = (ox < 30) && (gxo < IMG);
    const float b20 = b2[0], b21 = b2[1], b22 = b2[2], b23 = b2[3];
    const int n4 = n * 4;
    int ph0 = ox + 0, ph1 = ox + 1, ph2 = ox + 2;
    ph2 = ph2 < 31 ? ph2 : 31;
    ph1 = ph1 < 31 ? ph1 : 31;
    const int ba0 = ph0 * 64 + ((cg ^ (((ph0 >> 1) ^ (ph0 >> 3)) & 3)) << 4);
    const int ba1 = ph1 * 64 + ((cg ^ (((ph1 >> 1) ^ (ph1 >> 3)) & 3)) << 4);
    const int ba2 = ph2 * 64 + ((cg ^ (((ph2 >> 1) ^ (ph2 >> 3)) & 3)) << 4);
    const char* hbA = (const char*)hs + (ybq * 8) * 2048;
    const char* hbB = hbA + 4 * 2048;
    f32x4 CA = {b20, b21, b22, b23};  // bias pre-folded into accumulator
    f32x4 CB = {b20, b21, b22, b23};

#define C2(S, DYY, BA)                                                        \
  CA = __builtin_amdgcn_mfma_f32_16x16x32_bf16(                               \
      A2_##S, *(const short8*)(hbA + (DYY)*2048 + (BA)), CA, 0, 0, 0);        \
  CB = __builtin_amdgcn_mfma_f32_16x16x32_bf16(                               \
      A2_##S, *(const short8*)(hbB + (DYY)*2048 + (BA)), CB, 0, 0, 0);

    C2(0, 0, ba0) C2(1, 0, ba1) C2(2, 0, ba2)
    C2(3, 1, ba0) C2(4, 1, ba1) C2(5, 1, ba2)
    C2(6, 2, ba0) C2(7, 2, ba1) C2(8, 2, ba2)
    C2(9, 3, ba0) C2(10, 3, ba1) C2(11, 3, ba2)
    C2(12, 4, ba0) C2(13, 4, ba1) C2(14, 4, ba2)
    C2(15, 5, ba0) C2(16, 5, ba1) C2(17, 5, ba2)
#undef C2

#define EPI2(CV, YB)                                                          \
  if (epi_ok) {                                                               \
    const int gy = y0 + (YB) + yo;                                            \
    const long i0 = ((long)n4 * IMG + gy) * IMG + gxo;                        \
    out[i0] = fmaxf(CV[0], 0.f) * x[i0];                                      \
    out[i0 + CS] = fmaxf(CV[1], 0.f) * x[i0 + CS];                            \
    out[i0 + 2 * CS] = fmaxf(CV[2], 0.f) * x[i0 + 2 * CS];                    \
    out[i0 + 3 * CS] = fmaxf(CV[3], 0.f) * x[i0 + 3 * CS];                    \
  }
    EPI2(CA, ybq * 8)
    EPI2(CB, ybq * 8 + 4)
#undef EPI2
  }
}

// ---------------------------------------------------------------------------
extern "C" void kernel_launch(void* const* d_in, const int* in_sizes, int n_in,
                              void* d_out, int out_size, void* d_ws,
                              size_t ws_size, hipStream_t stream) {
  const float* x = (const float*)d_in[0];
  const float* w1 = (const float*)d_in[1];
  const float* b1 = (const float*)d_in[2];
  const float* w2 = (const float*)d_in[3];
  const float* b2 = (const float*)d_in[4];
  const float* w_se1 = (const float*)d_in[5];
  const float* b_se1 = (const float*)d_in[6];
  const float* w_se2 = (const float*)d_in[7];
  const float* b_se2 = (const float*)d_in[8];
  float* out = (float*)d_out;
  float* ws = (float*)d_ws;

  // ws: sums[512]f | w1f[1536]bf16 | w2f[147456]bf16 | partials[131072]f
  float* sums = ws;
  unsigned short* w1f = (unsigned short*)(ws + 512);
  unsigned short* w2f = w1f + 1536;
  float* partials = (float*)(w2f + 147456);
  const size_t need_full =
      512 * 4 + 1536 * 2 + (size_t)147456 * 2 + (size_t)131072 * 4;

  k_prep<<<1, 256, 0, stream>>>(w1, w1f);
  if (ws_size >= need_full) {
    k_pool<<<4096, 256, 0, stream>>>(x, w1f, b1, partials, 0);
    k_se<<<16, 256, 0, stream>>>(partials, sums, w_se1, b_se1, w_se2, b_se2,
                                 w2, w2f, 1);
  } else {
    hipMemsetAsync(sums, 0, 512 * sizeof(float), stream);
    k_pool<<<4096, 256, 0, stream>>>(x, w1f, b1, sums, 1);
    k_se<<<16, 256, 0, stream>>>(partials, sums, w_se1, b_se1, w_se2, b_se2,
                                 w2, w2f, 0);
  }
  k_main<<<9216, 256, 0, stream>>>(x, w1f, b1, w2f, b2, out);
}

// Round 8
// 102.517 us; speedup vs baseline: 9.8721x; 1.0289x over previous
//
#include <hip/hip_runtime.h>
#include <math.h>

#define IMG 512

typedef __attribute__((ext_vector_type(4))) short short4_t;
typedef __attribute__((ext_vector_type(8))) short short8;
typedef __attribute__((ext_vector_type(4))) float f32x4;
typedef __attribute__((ext_vector_type(16))) float f32x16;
typedef __attribute__((ext_vector_type(2))) unsigned int u32x2;

__device__ __forceinline__ unsigned short f2bf(float f) {
  unsigned u = __builtin_bit_cast(unsigned, f);
  u += 0x7FFFu + ((u >> 16) & 1u);  // RNE
  return (unsigned short)(u >> 16);
}
// packed f32x2 -> bf16x2 (RNE), single VALU op
__device__ __forceinline__ unsigned cvtpk(float lo, float hi) {
  unsigned r;
  asm("v_cvt_pk_bf16_f32 %0, %1, %2" : "=v"(r) : "v"(lo), "v"(hi));
  return r;
}

// ---------------------------------------------------------------------------
// k_prep: lane-major conv1 A-fragments (32x32x16, K padded 12->16 per kk=dy).
// ---------------------------------------------------------------------------
__global__ __launch_bounds__(256) void k_prep(const float* __restrict__ w1,
                                              unsigned short* __restrict__ w1f) {
  const int t = threadIdx.x;
  if (t < 192) {
    const int kk = t >> 6, lane = t & 63;
    const int oc = lane & 31, hi = lane >> 5;
#pragma unroll
    for (int j = 0; j < 8; ++j) {
      const int dxp = 2 * hi + (j >> 2), ic = j & 3;
      float v = (dxp < 3) ? w1[((oc * 4 + ic) * 3 + kk) * 3 + dxp] : 0.f;
      w1f[(kk * 64 + lane) * 8 + j] = f2bf(v);
    }
  }
}

// ---------------------------------------------------------------------------
// Pass 1: conv1 (bf16 MFMA 32x32x16) + ReLU + pool over exact 32x32 tiles.
// xs: channels-last bf16 [row 34][col 40][ic 4]; col delta = x0-1-sx = 3.
// Sliding-window B-frags: consecutive rows per wave, 3-cycle reg rotation.
// ---------------------------------------------------------------------------
__global__ __launch_bounds__(256, 3) void k_pool(
    const float* __restrict__ x, const unsigned short* __restrict__ w1f,
    const float* __restrict__ b1, float* __restrict__ red_out, int use_atomic) {
  __shared__ unsigned short xs[34 * 40 * 4];
  __shared__ float pools[4][2][16];
  const int bid = blockIdx.x;
  const int swz = (bid & 7) * 512 + (bid >> 3);  // XCD-contiguous
  const int bx = swz & 15, by = (swz >> 4) & 15, n = swz >> 8;
  const int x0 = bx * 32, y0 = by * 32;
  const int t = threadIdx.x, lane = t & 63, wv = t >> 6;
  const int hi = lane >> 5;

  short8 A1[3];
#pragma unroll
  for (int kk = 0; kk < 3; ++kk)
    A1[kk] = *(const short8*)&w1f[(kk * 64 + lane) * 8];
  float bias_r[16];
#pragma unroll
  for (int r = 0; r < 16; ++r) {
    float bl = b1[(r & 3) + 8 * (r >> 2)], bh = b1[(r & 3) + 8 * (r >> 2) + 4];
    bias_r[r] = hi ? bh : bl;
  }

  const int sx = x0 - 4;
  const long CS = (long)IMG * IMG;
  for (int i = t; i < 340; i += 256) {
    const int row = i / 10, cb = i % 10;
    const int gy = y0 - 1 + row, gx0 = sx + cb * 4;
    f32x4 v0 = {0.f, 0.f, 0.f, 0.f}, v1 = v0, v2 = v0, v3 = v0;
    if (gy >= 0 && gy < IMG && gx0 >= 0 && gx0 < IMG) {
      const float* p = x + (((long)(n * 4) * IMG + gy) * IMG + gx0);
      v0 = *(const f32x4*)p;
      v1 = *(const f32x4*)(p + CS);
      v2 = *(const f32x4*)(p + 2 * CS);
      v3 = *(const f32x4*)(p + 3 * CS);
    }
    unsigned short* d = &xs[(row * 40 + cb * 4) * 4];
#pragma unroll
    for (int j = 0; j < 4; ++j) {
      u32x2 w;
      w[0] = cvtpk(v0[j], v1[j]);
      w[1] = cvtpk(v2[j], v3[j]);
      *(u32x2*)(d + j * 4) = w;
    }
  }
  __syncthreads();

  float pacc[16];
#pragma unroll
  for (int r = 0; r < 16; ++r) pacc[r] = 0.f;
  const int cx0 = (lane & 31) + 2 * hi + 3;
  const unsigned short* pP = &xs[((wv * 8) * 40 + cx0) * 4];
#define LOADP(K)                                                              \
  __builtin_shufflevector(*(const short4_t*)(pP + (K)*160),                   \
                          *(const short4_t*)(pP + (K)*160 + 4), 0, 1, 2, 3,   \
                          4, 5, 6, 7)
  short8 Ba, Bb, Bc;
  Ba = LOADP(0);
  Bb = LOADP(1);
#define P_ITER(IT, B0, B1, B2)                                                \
  {                                                                           \
    B2 = LOADP((IT) + 2);                                                     \
    f32x16 C;                                                                 \
    _Pragma("unroll") for (int r = 0; r < 16; ++r) C[r] = bias_r[r];          \
    C = __builtin_amdgcn_mfma_f32_32x32x16_bf16(A1[0], B0, C, 0, 0, 0);       \
    C = __builtin_amdgcn_mfma_f32_32x32x16_bf16(A1[1], B1, C, 0, 0, 0);       \
    C = __builtin_amdgcn_mfma_f32_32x32x16_bf16(A1[2], B2, C, 0, 0, 0);       \
    _Pragma("unroll") for (int r = 0; r < 16; ++r)                            \
        pacc[r] += fmaxf(C[r], 0.f);                                          \
  }
  P_ITER(0, Ba, Bb, Bc)
  P_ITER(1, Bb, Bc, Ba)
  P_ITER(2, Bc, Ba, Bb)
  P_ITER(3, Ba, Bb, Bc)
  P_ITER(4, Bb, Bc, Ba)
  P_ITER(5, Bc, Ba, Bb)
  P_ITER(6, Ba, Bb, Bc)
  P_ITER(7, Bb, Bc, Ba)
#undef P_ITER
#undef LOADP
#pragma unroll
  for (int r = 0; r < 16; ++r) {
#pragma unroll
    for (int m = 1; m < 32; m <<= 1) pacc[r] += __shfl_xor(pacc[r], m);
  }
  if ((lane & 31) == 0) {
#pragma unroll
    for (int r = 0; r < 16; ++r) pools[wv][hi][r] = pacc[r];
  }
  __syncthreads();
  if (t < 32) {
    const int c = t;
    const int hic = (c >> 2) & 1, reg = (c & 3) + 4 * (c >> 3);
    float s = pools[0][hic][reg] + pools[1][hic][reg] + pools[2][hic][reg] +
              pools[3][hic][reg];
    if (use_atomic) {
      atomicAdd(&red_out[n * 32 + c], s);
    } else {
      red_out[(n * 256 + by * 16 + bx) * 32 + c] = s;
    }
  }
}

// ---------------------------------------------------------------------------
// Pass 2: reduce partials (det path) + SE head + emit conv2 A-fragments:
// w2f[((n*18+s)*64+lane)*8+j], s=(dyy*3+dx), lane:(row16=oc+4*yo, cg),
// value = (0<=dyy-yo<3) ? w2[oc][c=cg*8+j][dyy-yo][dx]*p[c] : 0
// ---------------------------------------------------------------------------
__global__ __launch_bounds__(256) void k_se(
    const float* __restrict__ partials, const float* __restrict__ sums,
    const float* __restrict__ w_se1, const float* __restrict__ b_se1,
    const float* __restrict__ w_se2, const float* __restrict__ b_se2,
    const float* __restrict__ w2, unsigned short* __restrict__ w2f, int det) {
  const int n = blockIdx.x, t = threadIdx.x;
  __shared__ float red[8][32];
  __shared__ float mean_s[32], f1[16], p[32];
  if (det) {
    const int c = t & 31, s = t >> 5;
    float a = 0.f;
    for (int i = s * 32; i < s * 32 + 32; ++i)
      a += partials[(n * 256 + i) * 32 + c];
    red[s][c] = a;
    __syncthreads();
    if (t < 32) {
      float v = 0.f;
#pragma unroll
      for (int s2 = 0; s2 < 8; ++s2) v += red[s2][t];
      mean_s[t] = v * (1.0f / (512.f * 512.f));
    }
  } else {
    if (t < 32) mean_s[t] = sums[n * 32 + t] * (1.0f / (512.f * 512.f));
  }
  __syncthreads();
  if (t < 16) {
    float a = b_se1[t];
#pragma unroll
    for (int c = 0; c < 32; ++c) a += w_se1[t * 32 + c] * mean_s[c];
    f1[t] = fmaxf(a, 0.f);
  }
  __syncthreads();
  if (t < 32) {
    float a = b_se2[t];
#pragma unroll
    for (int c = 0; c < 16; ++c) a += w_se2[t * 16 + c] * f1[c];
    p[t] = 1.f / (1.f + expf(-a));
  }
  __syncthreads();
  for (int i = t; i < 9216; i += 256) {
    const int s = i >> 9, rem = i & 511, lane2 = rem >> 3, j = rem & 7;
    const int oc = lane2 & 3, yo = (lane2 >> 2) & 3, cg = lane2 >> 4;
    const int c = cg * 8 + j;
    const int dyy = s / 3, dx = s - dyy * 3, dy = dyy - yo;
    float v = 0.f;
    if (dy >= 0 && dy < 3) v = w2[(oc * 32 + c) * 9 + dy * 3 + dx] * p[c];
    w2f[((n * 18 + s) * 64 + lane2) * 8 + j] = f2bf(v);
  }
}

// ---------------------------------------------------------------------------
// Pass 3: fused conv1(MFMA 32x32x16) -> hs(LDS) -> conv2(MFMA 16x16x32,
// full-M K=576) + residual multiply. Tile 30 out cols x 16 out rows.
// hs [18 rows][32 px][32 c] bf16, swizzle q2=(px>>1)&3 on 16B blocks
// (round-6 form: round-7's xor variant REGRESSED conflicts 4.0M->9.9M).
// conv2: 10 row-levels, 3 frags/level shared by chains A and B at levels
// 4-5 (30 ds_read_b128 instead of 36); setprio(1) around the MFMA cluster.
// ---------------------------------------------------------------------------
__global__ __launch_bounds__(256, 3) void k_main(
    const float* __restrict__ x, const unsigned short* __restrict__ w1f,
    const float* __restrict__ b1, const unsigned short* __restrict__ w2f,
    const float* __restrict__ b2, float* __restrict__ out) {
  __shared__ unsigned short xs[20 * 40 * 4];
  __shared__ unsigned short hs[18 * 32 * 32];
  const int bid = blockIdx.x;
  const int swz = (bid & 7) * 1152 + (bid >> 3);  // XCD-contiguous
  const int bx = swz % 18;
  const int q = swz / 18;
  const int by = q & 31, n = q >> 5;
  const int x0 = bx * 30, y0 = by * 16;
  const int t = threadIdx.x, lane = t & 63, wv = t >> 6;
  const int hi = lane >> 5;

  short8 A1[3];
#pragma unroll
  for (int kk = 0; kk < 3; ++kk)
    A1[kk] = *(const short8*)&w1f[(kk * 64 + lane) * 8];
  float bias_r[16];
#pragma unroll
  for (int r = 0; r < 16; ++r) {
    float bl = b1[(r & 3) + 8 * (r >> 2)], bh = b1[(r & 3) + 8 * (r >> 2) + 4];
    bias_r[r] = hi ? bh : bl;
  }

  const int sx = (x0 - 4) & ~3;
  const long CS = (long)IMG * IMG;
  for (int i = t; i < 200; i += 256) {
    const int row = i / 10, cb = i % 10;
    const int gy = y0 - 2 + row, gx0 = sx + cb * 4;
    f32x4 v0 = {0.f, 0.f, 0.f, 0.f}, v1 = v0, v2 = v0, v3 = v0;
    if (gy >= 0 && gy < IMG && gx0 >= 0 && gx0 < IMG) {
      const float* p = x + (((long)(n * 4) * IMG + gy) * IMG + gx0);
      v0 = *(const f32x4*)p;
      v1 = *(const f32x4*)(p + CS);
      v2 = *(const f32x4*)(p + 2 * CS);
      v3 = *(const f32x4*)(p + 3 * CS);
    }
    unsigned short* d = &xs[(row * 40 + cb * 4) * 4];
#pragma unroll
    for (int j = 0; j < 4; ++j) {
      u32x2 w;
      w[0] = cvtpk(v0[j], v1[j]);
      w[1] = cvtpk(v2[j], v3[j]);
      *(u32x2*)(d + j * 4) = w;
    }
  }
  __syncthreads();

  // ---- conv1 -> hs (hs = 0 outside image: conv2 zero-pads ITS input)
  {
    const int px = lane & 31;
    const int cx0 = px + 2 * hi + (x0 - 2 - sx);  // halo-aware delta
    const int q2 = (px >> 1) & 3;
    const int gxc = x0 - 1 + px;
    const bool colok = (gxc >= 0) && (gxc < IMG);
    const bool col_int = (x0 >= 1) && (x0 + 30 < IMG);  // block-uniform
    const int R0 = (wv < 2) ? wv * 5 : 10 + (wv - 2) * 4;  // rows/wave 5,5,4,4
    const unsigned short* pR = &xs[(R0 * 40 + cx0) * 4];
#define LOADX(K)                                                              \
  __builtin_shufflevector(*(const short4_t*)(pR + (K)*160),                   \
                          *(const short4_t*)(pR + (K)*160 + 4), 0, 1, 2, 3,   \
                          4, 5, 6, 7)
    short8 Ba, Bb, Bc;
    Ba = LOADX(0);
    Bb = LOADX(1);
#define C1_ITER(IT, B0, B1, B2)                                               \
  {                                                                           \
    B2 = LOADX((IT) + 2);                                                     \
    const int hy = R0 + (IT);                                                 \
    const int yi = y0 - 1 + hy;                                               \
    const bool row_ok = (yi >= 0) && (yi < IMG);                              \
    f32x16 C;                                                                 \
    _Pragma("unroll") for (int r = 0; r < 16; ++r) C[r] = bias_r[r];          \
    C = __builtin_amdgcn_mfma_f32_32x32x16_bf16(A1[0], B0, C, 0, 0, 0);       \
    C = __builtin_amdgcn_mfma_f32_32x32x16_bf16(A1[1], B1, C, 0, 0, 0);       \
    C = __builtin_amdgcn_mfma_f32_32x32x16_bf16(A1[2], B2, C, 0, 0, 0);       \
    const int usb = hy * 1024 + px * 32 + (hi << 2);                          \
    if (row_ok && col_int) {                                                  \
      _Pragma("unroll") for (int g = 0; g < 4; ++g) {                         \
        u32x2 w;                                                              \
        w[0] = cvtpk(fmaxf(C[4 * g + 0], 0.f), fmaxf(C[4 * g + 1], 0.f));     \
        w[1] = cvtpk(fmaxf(C[4 * g + 2], 0.f), fmaxf(C[4 * g + 3], 0.f));     \
        *(u32x2*)&hs[usb + ((g ^ q2) << 3)] = w;                              \
      }                                                                       \
    } else if (row_ok) {                                                      \
      _Pragma("unroll") for (int g = 0; g < 4; ++g) {                         \
        unsigned p01 =                                                        \
            cvtpk(fmaxf(C[4 * g + 0], 0.f), fmaxf(C[4 * g + 1], 0.f));        \
        unsigned p23 =                                                        \
            cvtpk(fmaxf(C[4 * g + 2], 0.f), fmaxf(C[4 * g + 3], 0.f));        \
        u32x2 w;                                                              \
        w[0] = colok ? p01 : 0u;                                              \
        w[1] = colok ? p23 : 0u;                                              \
        *(u32x2*)&hs[usb + ((g ^ q2) << 3)] = w;                              \
      }                                                                       \
    } else {                                                                  \
      u32x2 z;                                                                \
      z[0] = 0u;                                                              \
      z[1] = 0u;                                                              \
      _Pragma("unroll") for (int g = 0; g < 4; ++g)                           \
          *(u32x2*)&hs[usb + ((g ^ q2) << 3)] = z;                            \
    }                                                                         \
  }
    C1_ITER(0, Ba, Bb, Bc)
    C1_ITER(1, Bb, Bc, Ba)
    C1_ITER(2, Bc, Ba, Bb)
    C1_ITER(3, Ba, Bb, Bc)
    if (wv < 2) C1_ITER(4, Bb, Bc, Ba)
#undef C1_ITER
#undef LOADX
  }

  // ---- conv2 A-frags: issue BEFORE barrier (overlap), pin in registers
  const unsigned short* w2b = w2f + (size_t)n * 9216 + lane * 8;
  short8 A2_0 = *(const short8*)(w2b + 0 * 512);
  short8 A2_1 = *(const short8*)(w2b + 1 * 512);
  short8 A2_2 = *(const short8*)(w2b + 2 * 512);
  short8 A2_3 = *(const short8*)(w2b + 3 * 512);
  short8 A2_4 = *(const short8*)(w2b + 4 * 512);
  short8 A2_5 = *(const short8*)(w2b + 5 * 512);
  short8 A2_6 = *(const short8*)(w2b + 6 * 512);
  short8 A2_7 = *(const short8*)(w2b + 7 * 512);
  short8 A2_8 = *(const short8*)(w2b + 8 * 512);
  short8 A2_9 = *(const short8*)(w2b + 9 * 512);
  short8 A2_10 = *(const short8*)(w2b + 10 * 512);
  short8 A2_11 = *(const short8*)(w2b + 11 * 512);
  short8 A2_12 = *(const short8*)(w2b + 12 * 512);
  short8 A2_13 = *(const short8*)(w2b + 13 * 512);
  short8 A2_14 = *(const short8*)(w2b + 14 * 512);
  short8 A2_15 = *(const short8*)(w2b + 15 * 512);
  short8 A2_16 = *(const short8*)(w2b + 16 * 512);
  short8 A2_17 = *(const short8*)(w2b + 17 * 512);
  asm volatile("" ::"v"(A2_0), "v"(A2_1), "v"(A2_2), "v"(A2_3), "v"(A2_4),
               "v"(A2_5), "v"(A2_6), "v"(A2_7), "v"(A2_8), "v"(A2_9),
               "v"(A2_10), "v"(A2_11), "v"(A2_12), "v"(A2_13), "v"(A2_14),
               "v"(A2_15), "v"(A2_16), "v"(A2_17));
  __syncthreads();

  // ---- conv2: 10 row-levels, frags shared by both chains at levels 4-5
  {
    const int px16 = lane & 15, cg = lane >> 4;
    const int grp = wv & 1, ybq = wv >> 1;
    const int ox = grp * 16 + px16;
    const int yo = lane >> 4;
    const int gxo = x0 + ox;
    const bool epi_ok = (ox < 30) && (gxo < IMG);
    const float b20 = b2[0], b21 = b2[1], b22 = b2[2], b23 = b2[3];
    const int n4 = n * 4;
    int ph0 = ox + 0, ph1 = ox + 1, ph2 = ox + 2;
    ph2 = ph2 < 31 ? ph2 : 31;
    ph1 = ph1 < 31 ? ph1 : 31;
    const int ba0 = ph0 * 64 + ((cg ^ ((ph0 >> 1) & 3)) << 4);
    const int ba1 = ph1 * 64 + ((cg ^ ((ph1 >> 1) & 3)) << 4);
    const int ba2 = ph2 * 64 + ((cg ^ ((ph2 >> 1) & 3)) << 4);
    const char* hb = (const char*)hs + (ybq * 8) * 2048;
    f32x4 CA = {b20, b21, b22, b23};  // bias pre-folded into accumulator
    f32x4 CB = {b20, b21, b22, b23};
    short8 F0, F1, F2;

#define LOADF(R)                                                              \
  F0 = *(const short8*)(hb + (R)*2048 + ba0);                                 \
  F1 = *(const short8*)(hb + (R)*2048 + ba1);                                 \
  F2 = *(const short8*)(hb + (R)*2048 + ba2);
#define MFA(S0, S1, S2)                                                       \
  CA = __builtin_amdgcn_mfma_f32_16x16x32_bf16(A2_##S0, F0, CA, 0, 0, 0);     \
  CA = __builtin_amdgcn_mfma_f32_16x16x32_bf16(A2_##S1, F1, CA, 0, 0, 0);     \
  CA = __builtin_amdgcn_mfma_f32_16x16x32_bf16(A2_##S2, F2, CA, 0, 0, 0);
#define MFB(S0, S1, S2)                                                       \
  CB = __builtin_amdgcn_mfma_f32_16x16x32_bf16(A2_##S0, F0, CB, 0, 0, 0);     \
  CB = __builtin_amdgcn_mfma_f32_16x16x32_bf16(A2_##S1, F1, CB, 0, 0, 0);     \
  CB = __builtin_amdgcn_mfma_f32_16x16x32_bf16(A2_##S2, F2, CB, 0, 0, 0);

    __builtin_amdgcn_s_setprio(1);
    LOADF(0) MFA(0, 1, 2)
    LOADF(1) MFA(3, 4, 5)
    LOADF(2) MFA(6, 7, 8)
    LOADF(3) MFA(9, 10, 11)
    LOADF(4) MFA(12, 13, 14) MFB(0, 1, 2)
    LOADF(5) MFA(15, 16, 17) MFB(3, 4, 5)
    LOADF(6) MFB(6, 7, 8)
    LOADF(7) MFB(9, 10, 11)
    LOADF(8) MFB(12, 13, 14)
    LOADF(9) MFB(15, 16, 17)
    __builtin_amdgcn_s_setprio(0);
#undef LOADF
#undef MFA
#undef MFB

#define EPI2(CV, YB)                                                          \
  if (epi_ok) {                                                               \
    const int gy = y0 + (YB) + yo;                                            \
    const long i0 = ((long)n4 * IMG + gy) * IMG + gxo;                        \
    out[i0] = fmaxf(CV[0], 0.f) * x[i0];                                      \
    out[i0 + CS] = fmaxf(CV[1], 0.f) * x[i0 + CS];                            \
    out[i0 + 2 * CS] = fmaxf(CV[2], 0.f) * x[i0 + 2 * CS];                    \
    out[i0 + 3 * CS] = fmaxf(CV[3], 0.f) * x[i0 + 3 * CS];                    \
  }
    EPI2(CA, ybq * 8)
    EPI2(CB, ybq * 8 + 4)
#undef EPI2
  }
}

// ---------------------------------------------------------------------------
extern "C" void kernel_launch(void* const* d_in, const int* in_sizes, int n_in,
                              void* d_out, int out_size, void* d_ws,
                              size_t ws_size, hipStream_t stream) {
  const float* x = (const float*)d_in[0];
  const float* w1 = (const float*)d_in[1];
  const float* b1 = (const float*)d_in[2];
  const float* w2 = (const float*)d_in[3];
  const float* b2 = (const float*)d_in[4];
  const float* w_se1 = (const float*)d_in[5];
  const float* b_se1 = (const float*)d_in[6];
  const float* w_se2 = (const float*)d_in[7];
  const float* b_se2 = (const float*)d_in[8];
  float* out = (float*)d_out;
  float* ws = (float*)d_ws;

  // ws: sums[512]f | w1f[1536]bf16 | w2f[147456]bf16 | partials[131072]f
  float* sums = ws;
  unsigned short* w1f = (unsigned short*)(ws + 512);
  unsigned short* w2f = w1f + 1536;
  float* partials = (float*)(w2f + 147456);
  const size_t need_full =
      512 * 4 + 1536 * 2 + (size_t)147456 * 2 + (size_t)131072 * 4;

  k_prep<<<1, 256, 0, stream>>>(w1, w1f);
  if (ws_size >= need_full) {
    k_pool<<<4096, 256, 0, stream>>>(x, w1f, b1, partials, 0);
    k_se<<<16, 256, 0, stream>>>(partials, sums, w_se1, b_se1, w_se2, b_se2,
                                 w2, w2f, 1);
  } else {
    hipMemsetAsync(sums, 0, 512 * sizeof(float), stream);
    k_pool<<<4096, 256, 0, stream>>>(x, w1f, b1, sums, 1);
    k_se<<<16, 256, 0, stream>>>(partials, sums, w_se1, b_se1, w_se2, b_se2,
                                 w2, w2f, 0);
  }
  k_main<<<9216, 256, 0, stream>>>(x, w1f, b1, w2f, b2, out);
}